// Round 20
// baseline (988.026 us; speedup 1.0000x reference)
//
#include <hip/hip_runtime.h>

#define HD 128
#define GNUM 512
#define RPB 520   // per-type stride in rpb_all (>= GNUM+1)
#define IDXCAP 512
#define TM 32     // GEMM tile rows (32 -> 19.5 KB LDS -> ~8 blocks/CU)

typedef __attribute__((ext_vector_type(8))) short short8v;   // 8 bf16 = 4 VGPR
typedef __attribute__((ext_vector_type(4))) float f32x4;

// RNE split: a ~= hi + lo (both bf16), |residual| ~ 2^-17 |a|
__device__ __forceinline__ void split1(float a, short& h, short& l) {
  unsigned u = __float_as_uint(a);
  unsigned hb = (u + 0x7FFFu + ((u >> 16) & 1u)) & 0xFFFF0000u;
  h = (short)(hb >> 16);
  float rest = a - __uint_as_float(hb);
  unsigned u2 = __float_as_uint(rest);
  l = (short)((u2 + 0x7FFFu + ((u2 >> 16) & 1u)) >> 16);
}

// ============ W pre-split: fp32 [k][n] -> bf16 hi/lo TRANSPOSED [n][k] ============
struct WTab { const float* p[8]; };
__global__ __launch_bounds__(256) void k_split_w(WTab tab, short* __restrict__ whi,
                                                 short* __restrict__ wlo)
{
  int m = blockIdx.x >> 6;                       // 16 matrices, 64 blocks each
  int i = (blockIdx.x & 63) * 256 + threadIdx.x; // 0..16383
  const float* W = tab.p[m >> 1] + (m & 1) * 16384;
  int k = i >> 7, n = i & 127;
  short h, l;
  split1(W[k * 128 + n], h, l);
  whi[m * 16384 + n * 128 + k] = h;
  wlo[m * 16384 + n * 128 + k] = l;
}

// ============ MFMA GEMM: C = A1@W1 (+ A2@W2) (+bias, relu) ====================
// 32-row tile, 4 waves of 32r x 32c -> ~19.5 KB LDS -> high occupancy.
// If grp/gcol given: A1 rows are CSR-MEAN over gcol of A1 (SAGE fusion); the
// block's edge slice is prefetched to LDS; 2-way unrolled edge loop.
// Optional fused row-dot: adot[r] = (A1@W1)_row[r] . avec  (avec in OUTPUT space).
#define CF_LD 132
__global__ __launch_bounds__(256) void k_gemm_mfma(
    const float* __restrict__ A1, const short* __restrict__ WH1, const short* __restrict__ WL1,
    const int* __restrict__ grp, const int* __restrict__ gcol,
    const float* __restrict__ A2, const short* __restrict__ WH2, const short* __restrict__ WL2,
    float* __restrict__ C, const float* __restrict__ bias, int N, int relu,
    const float* __restrict__ avec, float* __restrict__ adot)
{
  __shared__ char smem[TM * 136 * 2 * 2];        // 17408 B
  __shared__ int idxbuf[IDXCAP];                 // 2048 B (19456 total)
  short* Ah = (short*)smem;
  short* Al = Ah + TM * 136;
  float* Cf = (float*)smem;                      // TM*132*4 = 16896 <= 17408

  const int t = threadIdx.x;
  const int row0 = blockIdx.x * TM;
  const int lane = t & 63, wid = t >> 6;
  const int g = lane >> 4, cn = lane & 15;
  const int colbase = wid * 32;

  f32x4 zero = {0.f, 0.f, 0.f, 0.f};
  f32x4 acc[2][2];
#pragma unroll
  for (int rt = 0; rt < 2; ++rt) { acc[rt][0] = zero; acc[rt][1] = zero; }

  auto stageA = [&](const float* __restrict__ A) {
    const float4* A4 = (const float4*)(A + (size_t)row0 * 128);
#pragma unroll
    for (int i = 0; i < 4; ++i) {
      int f4 = t + i * 256;
      int row = f4 >> 5, c4 = f4 & 31;
      float4 v = make_float4(0.f, 0.f, 0.f, 0.f);
      if (row0 + row < N) v = A4[f4];
      short4 h, l;
      split1(v.x, h.x, l.x); split1(v.y, h.y, l.y);
      split1(v.z, h.z, l.z); split1(v.w, h.w, l.w);
      *(short4*)(Ah + row * 136 + c4 * 4) = h;
      *(short4*)(Al + row * 136 + c4 * 4) = l;
    }
  };

  // CSR-mean gather staging: 32-thread group per row; LDS indices; 2-way unroll.
  auto stageA_gather = [&](const float* __restrict__ X, int e_lo) {
#pragma unroll
    for (int i = 0; i < 4; ++i) {
      int f4 = t + i * 256;
      int row = f4 >> 5, ln = f4 & 31;
      int r = row0 + row;
      float4 s = make_float4(0.f, 0.f, 0.f, 0.f);
      int e0 = 0, e1 = 0;
      if (r < N) { e0 = grp[r]; e1 = grp[r + 1]; }
      int e = e0;
      for (; e + 1 < e1; e += 2) {
        int off0 = e - e_lo, off1 = off0 + 1;
        int c0 = (off0 < IDXCAP) ? idxbuf[off0] : gcol[e];
        int c1 = (off1 < IDXCAP) ? idxbuf[off1] : gcol[e + 1];
        float4 v0 = *(const float4*)(X + (size_t)c0 * 128 + ln * 4);
        float4 v1 = *(const float4*)(X + (size_t)c1 * 128 + ln * 4);
        s.x += v0.x + v1.x; s.y += v0.y + v1.y;
        s.z += v0.z + v1.z; s.w += v0.w + v1.w;
      }
      if (e < e1) {
        int off = e - e_lo;
        int c = (off < IDXCAP) ? idxbuf[off] : gcol[e];
        float4 v = *(const float4*)(X + (size_t)c * 128 + ln * 4);
        s.x += v.x; s.y += v.y; s.z += v.z; s.w += v.w;
      }
      float inv = 1.f / fmaxf((float)(e1 - e0), 1.f);
      short4 h, l;
      split1(s.x * inv, h.x, l.x); split1(s.y * inv, h.y, l.y);
      split1(s.z * inv, h.z, l.z); split1(s.w * inv, h.w, l.w);
      *(short4*)(Ah + row * 136 + ln * 4) = h;
      *(short4*)(Al + row * 136 + ln * 4) = l;
    }
  };

  auto accum = [&](const short* __restrict__ WH, const short* __restrict__ WL) {
#pragma unroll
    for (int kg = 0; kg < 4; ++kg) {
      short8v bhi[2], blo[2];
#pragma unroll
      for (int ct = 0; ct < 2; ++ct) {
        size_t o = (size_t)(colbase + ct * 16 + cn) * 128 + kg * 32 + g * 8;
        bhi[ct] = *(const short8v*)(WH + o);
        blo[ct] = *(const short8v*)(WL + o);
      }
#pragma unroll
      for (int rt = 0; rt < 2; ++rt) {
        const int ao = (rt * 16 + cn) * 136 + kg * 32 + g * 8;
        const short8v ah = *(const short8v*)(Ah + ao);
        const short8v al = *(const short8v*)(Al + ao);
#pragma unroll
        for (int ct = 0; ct < 2; ++ct) {
          acc[rt][ct] = __builtin_amdgcn_mfma_f32_16x16x32_bf16(ah, bhi[ct], acc[rt][ct], 0, 0, 0);
          acc[rt][ct] = __builtin_amdgcn_mfma_f32_16x16x32_bf16(al, bhi[ct], acc[rt][ct], 0, 0, 0);
          acc[rt][ct] = __builtin_amdgcn_mfma_f32_16x16x32_bf16(ah, blo[ct], acc[rt][ct], 0, 0, 0);
        }
      }
    }
  };

  if (grp) {
    const int row_end = min(row0 + TM, N);
    const int e_lo = grp[row0];
    const int cnt = min(grp[row_end] - e_lo, IDXCAP);
    for (int k = t; k < cnt; k += 256) idxbuf[k] = gcol[e_lo + k];
    __syncthreads();
    stageA_gather(A1, e_lo);
  } else {
    stageA(A1);
  }
  __syncthreads();
  accum(WH1, WL1);
  if (A2) {
    __syncthreads();
    stageA(A2);
    __syncthreads();
    accum(WH2, WL2);
  }
  __syncthreads();                   // Ah/Al dead past here; smem reusable

  // ---- fused row-dot (raw A@W): per-wave partial + cross-wave LDS reduce ----
  if (avec) {
    float* part = (float*)smem;      // [4 waves][TM rows]
    const float av0 = avec[colbase + cn];
    const float av1 = avec[colbase + 16 + cn];
#pragma unroll
    for (int rt = 0; rt < 2; ++rt)
#pragma unroll
      for (int r = 0; r < 4; ++r) {
        float p = fmaf(acc[rt][1][r], av1, acc[rt][0][r] * av0);
#pragma unroll
        for (int o = 1; o < 16; o <<= 1) p += __shfl_xor(p, o);
        if (cn == 0) part[wid * TM + rt * 16 + g * 4 + r] = p;
      }
    __syncthreads();
    if (t < TM) {
      int row = row0 + t;
      if (row < N) adot[row] = part[t] + part[TM + t] + part[2 * TM + t] + part[3 * TM + t];
    }
    __syncthreads();
  }

  // scatter acc into LDS C-tile: C/D layout col = lane&15, row = (lane>>4)*4 + reg
#pragma unroll
  for (int rt = 0; rt < 2; ++rt)
#pragma unroll
    for (int ct = 0; ct < 2; ++ct)
#pragma unroll
      for (int r = 0; r < 4; ++r)
        Cf[(rt * 16 + g * 4 + r) * CF_LD + colbase + ct * 16 + cn] = acc[rt][ct][r];
  __syncthreads();

  float4* C4 = (float4*)(C + (size_t)row0 * 128);
#pragma unroll
  for (int i = 0; i < 4; ++i) {
    int f4 = t + i * 256;
    int row = f4 >> 5, c4 = f4 & 31;
    if (row0 + row < N) {
      float4 v = *(const float4*)(Cf + row * CF_LD + c4 * 4);
      if (bias) {
        float4 bv = *(const float4*)(bias + c4 * 4);
        v.x += bv.x; v.y += bv.y; v.z += bv.z; v.w += bv.w;
      }
      if (relu) {
        v.x = fmaxf(v.x, 0.f); v.y = fmaxf(v.y, 0.f);
        v.z = fmaxf(v.z, 0.f); v.w = fmaxf(v.w, 0.f);
      }
      C4[f4] = v;
    }
  }
}

// ======================= row dot: out[n] = x[n,:] . a  (one wave / node) ===========
__global__ void k_rowdot(const float* __restrict__ x, const float* __restrict__ a,
                         float* __restrict__ out, int N)
{
  int wid = blockIdx.x * 4 + (threadIdx.x >> 6);
  int lane = threadIdx.x & 63;
  if (wid >= N) return;
  float2 xv = ((const float2*)x)[(size_t)wid * 64 + lane];
  float2 av = ((const float2*)a)[lane];
  float v = fmaf(xv.y, av.y, xv.x * av.x);
#pragma unroll
  for (int o = 32; o > 0; o >>= 1) v += __shfl_down(v, o);
  if (lane == 0) out[wid] = v;
}

// ================= batched matvec: wv[m][i] = sum_j W_m[i,j]*a_m[j] ==============
struct MTab { const float* W[4]; const float* a[4]; };
__global__ __launch_bounds__(128) void k_matvec4(MTab tb, float* __restrict__ wv)
{
  __shared__ float as[128];
  int m = blockIdx.x, i = threadIdx.x;
  as[i] = tb.a[m][i];
  __syncthreads();
  const float* W = tb.W[m];
  float v = 0.f;
  for (int j = 0; j < 128; ++j) v = fmaf(W[i * 128 + j], as[j], v);
  wv[m * 128 + i] = v;
}

// ======================= batched CSR build =======================
struct HTab { const int* key[6]; int* cnt[6]; unsigned short* rank[6]; int bo[7]; int n[6]; };
__global__ void k_hist_rank_all(HTab tb) {
  int bi = blockIdx.x, ty = 0;
  while (ty < 5 && bi >= tb.bo[ty + 1]) ++ty;
  int i = (bi - tb.bo[ty]) * 256 + threadIdx.x;
  if (i < tb.n[ty])
    tb.rank[ty][i] = (unsigned short)atomicAdd(&tb.cnt[ty][tb.key[ty][i]], 1);
}

struct FTab { const int* es[6]; const int* ed[6]; const int* rp[6];
              const unsigned short* rank[6]; int* col[6]; int bo[7]; int n[6]; };
__global__ void k_fill_all(FTab tb) {
  int bi = blockIdx.x, ty = 0;
  while (ty < 5 && bi >= tb.bo[ty + 1]) ++ty;
  int e = (bi - tb.bo[ty]) * 256 + threadIdx.x;
  if (e >= tb.n[ty]) return;
  int p = tb.rp[ty][tb.ed[ty][e]] + (int)tb.rank[ty][e];
  tb.col[ty][p] = tb.es[ty][e];
}

// ---- batched 3-phase exclusive scan over 6 arrays (tile = 4096) ----
struct STab { int* rp[6]; int* bs[6]; int n[6]; int bo[7]; };

__global__ __launch_bounds__(256) void k_scan_partial_all(STab tb) {
  __shared__ int red[256];
  int bi = blockIdx.x, ty = 0;
  while (ty < 5 && bi >= tb.bo[ty + 1]) ++ty;
  int lb = bi - tb.bo[ty];
  const int* rp = tb.rp[ty];
  const int N = tb.n[ty];
  const int t = threadIdx.x, base = lb * 4096;
  int s = 0;
  for (int i = t; i < 4096; i += 256) {
    int idx = base + i;
    if (idx < N) s += rp[idx];
  }
  red[t] = s;
  __syncthreads();
  for (int ofs = 128; ofs > 0; ofs >>= 1) {
    if (t < ofs) red[t] += red[t + ofs];
    __syncthreads();
  }
  if (t == 0) tb.bs[ty][lb] = red[0];
}

__global__ __launch_bounds__(256) void k_scan_bsums_all(STab tb) {
  __shared__ int sh[256];
  const int ty = blockIdx.x;
  const int nb = (tb.n[ty] + 4095) / 4096;   // <= 25
  const int t = threadIdx.x;
  int v = (t < nb) ? tb.bs[ty][t] : 0;
  sh[t] = v;
  __syncthreads();
  for (int ofs = 1; ofs < 256; ofs <<= 1) {
    int u = (t >= ofs) ? sh[t - ofs] : 0;
    __syncthreads();
    sh[t] += u;
    __syncthreads();
  }
  if (t < nb) tb.bs[ty][t] = sh[t] - v;      // exclusive
  if (t == 255) tb.rp[ty][tb.n[ty]] = sh[255];  // total
}

__global__ __launch_bounds__(256) void k_scan_final_all(STab tb) {
  __shared__ int sh[4096 + 256];             // padded: i -> i + (i>>4)
  __shared__ int tsum[256];
  int bi = blockIdx.x, ty = 0;
  while (ty < 5 && bi >= tb.bo[ty + 1]) ++ty;
  int lb = bi - tb.bo[ty];
  int* rp = tb.rp[ty];
  const int N = tb.n[ty];
  const int t = threadIdx.x, base = lb * 4096;
  auto mp = [](int i) { return i + (i >> 4); };
#pragma unroll
  for (int i = 0; i < 16; ++i) {
    int idx = base + i * 256 + t;
    sh[mp(i * 256 + t)] = (idx < N) ? rp[idx] : 0;
  }
  __syncthreads();
  int s = 0;
#pragma unroll
  for (int j = 0; j < 16; ++j) s += sh[mp(t * 16 + j)];
  tsum[t] = s;
  __syncthreads();
  for (int ofs = 1; ofs < 256; ofs <<= 1) {
    int u = (t >= ofs) ? tsum[t - ofs] : 0;
    __syncthreads();
    tsum[t] += u;
    __syncthreads();
  }
  int pre = tsum[t] - s + tb.bs[ty][lb];
#pragma unroll
  for (int j = 0; j < 16; ++j) {
    int v = sh[mp(t * 16 + j)];
    sh[mp(t * 16 + j)] = pre;
    pre += v;
  }
  __syncthreads();
#pragma unroll
  for (int i = 0; i < 16; ++i) {
    int idx = base + i * 256 + t;
    if (idx < N) rp[idx] = sh[mp(i * 256 + t)];
  }
}

// ---- run-pointers for SORTED batch vectors via binary search (no atomics) ----
struct BTab { const int* b[5]; int n[5]; };
__global__ __launch_bounds__(512) void k_runptr(BTab tb, int* __restrict__ rpb_all) {
  const int ty = blockIdx.x;
  const int* b = tb.b[ty];
  const int N = tb.n[ty];
  const int t = threadIdx.x;                 // 0..511 = graph id
  int lo = 0, hi = N;
  while (lo < hi) {                          // lower_bound(b, t)
    int mid = (lo + hi) >> 1;
    if (b[mid] < t) lo = mid + 1; else hi = mid;
  }
  rpb_all[ty * RPB + t] = lo;
  if (t == 0) rpb_all[ty * RPB + GNUM] = N;
}

// dis for both GCN types in one launch
struct DTab { const int* rp[2]; float* dis[2]; int n[2]; int bo[3]; };
__global__ void k_dis2(DTab tb) {
  int bi = blockIdx.x, ty = (bi >= tb.bo[1]) ? 1 : 0;
  int n = (bi - tb.bo[ty]) * 256 + threadIdx.x;
  if (n < tb.n[ty]) tb.dis[ty][n] = rsqrtf((float)(tb.rp[ty][n + 1] - tb.rp[ty][n]) + 1.f);
}

// ======================= gather kernels =======================
__global__ void k_gcn_gather(const int* __restrict__ rp, const int* __restrict__ col,
                             const float* __restrict__ dis, const float* __restrict__ h,
                             const float* addin, const float* __restrict__ b,
                             float* out, int N,
                             const float* __restrict__ dvec, float* __restrict__ dout)
{
  int node = blockIdx.x * 4 + (threadIdx.x >> 6);
  if (node >= N) return;
  int lane = threadIdx.x & 63;
  int s0 = rp[node], deg = rp[node + 1] - s0;
  float rd = dis[node];
  const float2* h2 = (const float2*)h;
  float2 hself = h2[(size_t)node * 64 + lane];
  float2 bv = ((const float2*)b)[lane];
  float ad0 = 0.f, ad1 = 0.f;
  if (addin) {
    float2 a2 = ((const float2*)addin)[(size_t)node * 64 + lane];
    ad0 = a2.x; ad1 = a2.y;
  }
  float a0 = 0.f, a1 = 0.f, b0 = 0.f, b1 = 0.f;
  for (int base = 0; base < deg; base += 64) {
    int m = min(64, deg - base);
    int c = 0; float dv = 0.f;
    if (lane < m) { c = col[s0 + base + lane]; dv = dis[c]; }
    int j = 0;
    for (; j + 1 < m; j += 2) {
      int sA = __shfl(c, j), sB = __shfl(c, j + 1);
      float nA = __shfl(dv, j) * rd, nB = __shfl(dv, j + 1) * rd;
      float2 vA = h2[(size_t)sA * 64 + lane];
      float2 vB = h2[(size_t)sB * 64 + lane];
      a0 = fmaf(nA, vA.x, a0); a1 = fmaf(nA, vA.y, a1);
      b0 = fmaf(nB, vB.x, b0); b1 = fmaf(nB, vB.y, b1);
    }
    if (j < m) {
      int sA = __shfl(c, j);
      float nA = __shfl(dv, j) * rd;
      float2 vA = h2[(size_t)sA * 64 + lane];
      a0 = fmaf(nA, vA.x, a0); a1 = fmaf(nA, vA.y, a1);
    }
  }
  float rr = rd * rd;
  float v0 = fmaf(rr, hself.x, a0 + b0) + bv.x + ad0;
  float v1 = fmaf(rr, hself.y, a1 + b1) + bv.y + ad1;
  v0 = fmaxf(v0, 0.f); v1 = fmaxf(v1, 0.f);
  ((float2*)out)[(size_t)node * 64 + lane] = make_float2(v0, v1);
  if (dvec) {
    float2 wv = ((const float2*)dvec)[lane];
    float p = fmaf(v1, wv.y, v0 * wv.x);
#pragma unroll
    for (int o = 32; o > 0; o >>= 1) p += __shfl_xor(p, o);
    if (lane == 0) dout[node] = p;
  }
}

__global__ void k_gat_gather(const int* __restrict__ rp, const int* __restrict__ col,
                             const float* __restrict__ hs, const float* __restrict__ as_,
                             const float* __restrict__ ad_, const float* __restrict__ b,
                             float* __restrict__ out, int N, int relu,
                             const float* __restrict__ dvec, float* __restrict__ dout)
{
  int node = blockIdx.x * 4 + (threadIdx.x >> 6);
  if (node >= N) return;
  int lane = threadIdx.x & 63;
  int s0 = rp[node], deg = rp[node + 1] - s0;
  float adn = ad_[node];
  float2 bv = ((const float2*)b)[lane];
  const float2* hs2 = (const float2*)hs;
  float z = 0.f, a0 = 0.f, a1 = 0.f, b0 = 0.f, b1 = 0.f;
  for (int base = 0; base < deg; base += 64) {
    int m = min(64, deg - base);
    int c = 0; float av = 0.f;
    if (lane < m) { c = col[s0 + base + lane]; av = as_[c]; }
    int j = 0;
    for (; j + 1 < m; j += 2) {
      int sA = __shfl(c, j), sB = __shfl(c, j + 1);
      float vA = __shfl(av, j) + adn, vB = __shfl(av, j + 1) + adn;
      vA = vA > 0.f ? vA : 0.2f * vA;
      vB = vB > 0.f ? vB : 0.2f * vB;
      float pA = __expf(vA), pB = __expf(vB);
      z += pA + pB;
      float2 hA = hs2[(size_t)sA * 64 + lane];
      float2 hB = hs2[(size_t)sB * 64 + lane];
      a0 = fmaf(pA, hA.x, a0); a1 = fmaf(pA, hA.y, a1);
      b0 = fmaf(pB, hB.x, b0); b1 = fmaf(pB, hB.y, b1);
    }
    if (j < m) {
      int sA = __shfl(c, j);
      float vA = __shfl(av, j) + adn;
      vA = vA > 0.f ? vA : 0.2f * vA;
      float pA = __expf(vA);
      z += pA;
      float2 hA = hs2[(size_t)sA * 64 + lane];
      a0 = fmaf(pA, hA.x, a0); a1 = fmaf(pA, hA.y, a1);
    }
  }
  float inv = (deg > 0) ? 1.f / z : 0.f;
  float v0 = fmaf(a0 + b0, inv, bv.x);
  float v1 = fmaf(a1 + b1, inv, bv.y);
  if (relu) { v0 = fmaxf(v0, 0.f); v1 = fmaxf(v1, 0.f); }
  ((float2*)out)[(size_t)node * 64 + lane] = make_float2(v0, v1);
  if (dvec) {
    float2 wv = ((const float2*)dvec)[lane];
    float p = fmaf(v1, wv.y, v0 * wv.x);
#pragma unroll
    for (int o = 32; o > 0; o >>= 1) p += __shfl_xor(p, o);
    if (lane == 0) dout[node] = p;
  }
}

// ============ segment pooling: one block per graph, contiguous rows ============
__global__ __launch_bounds__(256) void k_pool_seg(
    const float* __restrict__ x, const int* __restrict__ rpb,
    float* __restrict__ pool, int col_off)
{
  __shared__ float2 red2[4][64];
  const int g = blockIdx.x;
  const int t = threadIdx.x, w = t >> 6, lane = t & 63;
  const int n0 = rpb[g], n1 = rpb[g + 1];
  const float2* x2 = (const float2*)x;
  float a0 = 0.f, a1 = 0.f, b0 = 0.f, b1 = 0.f;
  int n = n0 + w;
  for (; n + 4 < n1; n += 8) {
    float2 vA = x2[(size_t)n * 64 + lane];
    float2 vB = x2[(size_t)(n + 4) * 64 + lane];
    a0 += vA.x; a1 += vA.y; b0 += vB.x; b1 += vB.y;
  }
  if (n < n1) { float2 vA = x2[(size_t)n * 64 + lane]; a0 += vA.x; a1 += vA.y; }
  red2[w][lane] = make_float2(a0 + b0, a1 + b1);
  __syncthreads();
  if (t < 64) {
    float2 r0 = red2[0][t], r1 = red2[1][t], r2 = red2[2][t], r3 = red2[3][t];
    float inv = 1.f / fmaxf((float)(n1 - n0), 1.f);
    ((float2*)(pool + (size_t)g * 640 + col_off))[t] =
        make_float2((r0.x + r1.x + r2.x + r3.x) * inv,
                    (r0.y + r1.y + r2.y + r3.y) * inv);
  }
}

// ======================= final MLP (one block per graph) =======================
__global__ void k_mlp(const float* __restrict__ pool,
                      const float* __restrict__ W1, const float* __restrict__ b1,
                      const float* __restrict__ W2, const float* __restrict__ b2,
                      float* __restrict__ out)
{
  __shared__ float emb[640];
  __shared__ float red[128];
  const int g = blockIdx.x, t = threadIdx.x;
  for (int i = t; i < 640; i += 128) emb[i] = pool[(size_t)g * 640 + i];
  __syncthreads();
  float acc = b1[t];
  for (int i = 0; i < 640; ++i) acc = fmaf(emb[i], W1[i * 128 + t], acc);
  float h = fmaxf(acc, 0.f);
  red[t] = h * W2[t];
  __syncthreads();
  for (int s = 64; s > 0; s >>= 1) {
    if (t < s) red[t] += red[t + s];
    __syncthreads();
  }
  if (t == 0) out[g] = red[0] + b2[0];
}

// ======================= host =======================
extern "C" void kernel_launch(void* const* d_in, const int* in_sizes, int n_in,
                              void* d_out, int out_size, void* d_ws, size_t ws_size,
                              hipStream_t stream)
{
  auto fin = [&](int i) { return (const float*)d_in[i]; };
  auto iin = [&](int i) { return (const int*)d_in[i]; };

  const float *x_cd = fin(0), *x_seq = fin(1), *x_anno = fin(2), *x_range = fin(3), *x_md = fin(4);
  const int *ei_seq = iin(5), *ei_anno = iin(6), *ei_range = iin(7),
            *ei_comp = iin(8), *ei_cc = iin(9), *ei_mm = iin(10);
  const int *b_cd = iin(11), *b_seq = iin(12), *b_anno = iin(13), *b_range = iin(14), *b_md = iin(15);

  const int N_CD = in_sizes[0] / HD, N_SEQ = in_sizes[1] / HD, N_ANNO = in_sizes[2] / HD,
            N_RANGE = in_sizes[3] / HD, N_MD = in_sizes[4] / HD;
  const int E_seq = in_sizes[5] / 2, E_anno = in_sizes[6] / 2, E_range = in_sizes[7] / 2,
            E_comp = in_sizes[8] / 2, E_cc = in_sizes[9] / 2, E_mm = in_sizes[10] / 2;
  const int N_OTH = max(max(N_SEQ, N_ANNO), N_RANGE);

  auto WLm = [&](int i, int l) { return fin(i) + (size_t)l * HD * HD; };
  auto WLv = [&](int i, int l) { return fin(i) + (size_t)l * HD; };

  // ---- workspace layout ----
  float* ws = (float*)d_ws;
  size_t off = 0;
  auto alloc = [&](size_t n) { float* p = ws + off; off += (n + 3) & ~(size_t)3; return p; };
  float* xcd1 = alloc((size_t)N_CD * HD);
  float* xmd1 = alloc((size_t)N_MD * HD);
  float* xoth = alloc((size_t)N_OTH * HD);
  float* acc  = alloc((size_t)N_CD * HD);
  float* t1   = alloc((size_t)N_CD * HD);
  float* sAs  = alloc((size_t)N_CD);
  float* sAd  = alloc((size_t)N_CD);
  float* sAd2 = alloc((size_t)N_CD);
  float* dis_cc = alloc((size_t)N_CD);
  float* dis_mm = alloc((size_t)N_MD);
  float* wvall = alloc(4 * HD);
  float* pool = alloc((size_t)GNUM * 5 * HD);
  short* whi = (short*)(ws + off); off += (size_t)16 * 16384 / 2;
  short* wlo = (short*)(ws + off); off += (size_t)16 * 16384 / 2;
  auto alloci = [&](size_t n) { int* p = (int*)(ws + off); off += (n + 3) & ~(size_t)3; return p; };
  int* bsall = alloci(6 * 256);          // batched scan partials
  int* rpb_all = alloci(5 * RPB);
  int Nds[6] = {N_SEQ, N_ANNO, N_RANGE, N_CD, N_CD, N_MD};
  int Es[6]  = {E_seq, E_anno, E_range, E_comp, E_cc, E_mm};
  int* rps[6];
  int* rp0 = alloci(0);
  { size_t tot = 0; for (int i = 0; i < 6; ++i) tot += (size_t)Nds[i] + 1;
    int* p = alloci(tot); rp0 = p;
    for (int i = 0; i < 6; ++i) { rps[i] = p; p += Nds[i] + 1; } }
  size_t rp_tot_bytes = 0; for (int i = 0; i < 6; ++i) rp_tot_bytes += ((size_t)Nds[i] + 1) * 4;
  unsigned short* ranks[6];
  for (int i = 0; i < 6; ++i) ranks[i] = (unsigned short*)alloci(((size_t)Es[i] + 1) / 2);
  int* cols[6];  for (int i = 0; i < 6; ++i) cols[i] = alloci((size_t)Es[i]);
  (void)n_in;

  if (off * sizeof(float) > ws_size) {
    hipMemsetAsync(d_out, 0, (size_t)out_size * sizeof(float), stream);
    return;
  }

  auto ew = [&](size_t elems) { return dim3((unsigned)((elems + 255) / 256)); };
  auto nw = [&](int N) { return dim3((unsigned)((N + 3) / 4)); };

  // ---- pre-split all GEMM weights (slots: 0:16 1:18 2:19 3:21 4:22 5:27 6:32 7:34)
  WTab tab;
  tab.p[0] = fin(16); tab.p[1] = fin(18); tab.p[2] = fin(19); tab.p[3] = fin(21);
  tab.p[4] = fin(22); tab.p[5] = fin(27); tab.p[6] = fin(32); tab.p[7] = fin(34);
  k_split_w<<<dim3(1024), dim3(256), 0, stream>>>(tab, whi, wlo);

  // ---- 4 DST-side GAT matvecs (Wd@a_d): comp L0/L1, range L0/L1 ----
  MTab mt;
  mt.W[0] = WLm(23, 0); mt.a[0] = WLv(25, 0);
  mt.W[1] = WLm(23, 1); mt.a[1] = WLv(25, 1);
  mt.W[2] = WLm(28, 0); mt.a[2] = WLv(30, 0);
  mt.W[3] = WLm(28, 1); mt.a[3] = WLv(30, 1);
  k_matvec4<<<dim3(4), dim3(128), 0, stream>>>(mt, wvall);

  // ---- run-pointers for sorted batch vectors (binary search, no atomics) ----
  {
    BTab bt;
    bt.b[0] = b_cd; bt.n[0] = N_CD;  bt.b[1] = b_seq; bt.n[1] = N_SEQ;
    bt.b[2] = b_anno; bt.n[2] = N_ANNO;  bt.b[3] = b_range; bt.n[3] = N_RANGE;
    bt.b[4] = b_md; bt.n[4] = N_MD;
    k_runptr<<<dim3(5), dim3(512), 0, stream>>>(bt, rpb_all);
  }

  // ---- batched CSR build (rank-recording: fill has no atomics) ----
  const int* ess[6] = {ei_seq, ei_anno, ei_range, ei_comp, ei_cc, ei_mm};
  const int* eds[6] = {ei_seq + E_seq, ei_anno + E_anno, ei_range + E_range,
                       ei_comp + E_comp, ei_cc + E_cc, ei_mm + E_mm};
  hipMemsetAsync(rp0, 0, rp_tot_bytes, stream);
  {
    HTab ht; int b = 0;
    for (int i = 0; i < 6; ++i) {
      ht.key[i] = eds[i]; ht.cnt[i] = rps[i]; ht.rank[i] = ranks[i];
      ht.bo[i] = b; b += (Es[i] + 255) / 256; ht.n[i] = Es[i];
    }
    ht.bo[6] = b;
    k_hist_rank_all<<<dim3(b), dim3(256), 0, stream>>>(ht);
  }
  {
    STab st; int b = 0;
    for (int i = 0; i < 6; ++i) {
      st.rp[i] = rps[i]; st.bs[i] = bsall + i * 256;
      st.n[i] = Nds[i]; st.bo[i] = b; b += (Nds[i] + 4095) / 4096;
    }
    st.bo[6] = b;
    k_scan_partial_all<<<dim3(b), dim3(256), 0, stream>>>(st);
    k_scan_bsums_all<<<dim3(6), dim3(256), 0, stream>>>(st);
    k_scan_final_all<<<dim3(b), dim3(256), 0, stream>>>(st);
  }
  {
    FTab ft; int b = 0;
    for (int i = 0; i < 6; ++i) {
      ft.es[i] = ess[i]; ft.ed[i] = eds[i]; ft.rp[i] = rps[i]; ft.rank[i] = ranks[i];
      ft.col[i] = cols[i]; ft.bo[i] = b; b += (Es[i] + 255) / 256; ft.n[i] = Es[i];
    }
    ft.bo[6] = b;
    k_fill_all<<<dim3(b), dim3(256), 0, stream>>>(ft);
  }
  int *rp_seq = rps[0], *rp_anno = rps[1], *rp_range = rps[2],
      *rp_comp = rps[3], *rp_cc = rps[4], *rp_mm = rps[5];
  int *col_seq = cols[0], *col_anno = cols[1], *col_range = cols[2],
      *col_comp = cols[3], *col_cc = cols[4], *col_mm = cols[5];
  {
    DTab dt;
    dt.rp[0] = rp_cc; dt.dis[0] = dis_cc; dt.n[0] = N_CD;
    dt.rp[1] = rp_mm; dt.dis[1] = dis_mm; dt.n[1] = N_MD;
    dt.bo[0] = 0; dt.bo[1] = (N_CD + 255) / 256;
    dt.bo[2] = dt.bo[1] + (N_MD + 255) / 256;
    k_dis2<<<dim3(dt.bo[2]), dim3(256), 0, stream>>>(dt);
  }

  auto WHp = [&](int sidx, int layer) { return whi + (size_t)(sidx * 2 + layer) * 16384; };
  auto WLp = [&](int sidx, int layer) { return wlo + (size_t)(sidx * 2 + layer) * 16384; };
  auto gemm = [&](const float* A, int sidx, int layer, float* C, const float* b,
                  int N, int relu, const float* avec = nullptr, float* adot = nullptr) {
    k_gemm_mfma<<<dim3((N + TM - 1) / TM), dim3(256), 0, stream>>>(
        A, WHp(sidx, layer), WLp(sidx, layer), nullptr, nullptr,
        nullptr, nullptr, nullptr, C, b, N, relu, avec, adot);
  };
  // SAGE fused: A1 = CSR-mean of xsrc (LDS-index gather in staging), A2 = xself
  auto gemm2g = [&](const float* xsrc, const int* grp, const int* gcol, int s1,
                    const float* xself, int s2, int layer,
                    float* C, const float* b, int N) {
    k_gemm_mfma<<<dim3((N + TM - 1) / TM), dim3(256), 0, stream>>>(
        xsrc, WHp(s1, layer), WLp(s1, layer), grp, gcol,
        xself, WHp(s2, layer), WLp(s2, layer), C, b, N, 1, nullptr, nullptr);
  };
  auto do_pool = [&](const float* x, int type) {
    k_pool_seg<<<dim3(GNUM), dim3(256), 0, stream>>>(x, rpb_all + type * RPB, pool, type * HD);
  };

  // GAT: hs = xs@Ws with FUSED sAs = hs.a_s; sAd either precomputed (sAd_src)
  // or via rowdot(xd, wv). Optional fused out-dot (dvec->dout) for next layer.
  auto gat = [&](const float* xs, const float* xd, const int* rp, const int* col,
                 int Ns, int Nd, int sidx, int layer, const float* avs_raw,
                 const float* sAd_src, int wvD,
                 const float* dvec, float* dout,
                 const float* bias, float* out, int relu) {
    if (wvD >= 0) {
      k_rowdot<<<nw(Nd), dim3(256), 0, stream>>>(xd, wvall + wvD * 128, sAd, Nd);
      sAd_src = sAd;
    }
    gemm(xs, sidx, layer, t1, nullptr, Ns, 0, avs_raw, sAs);   // hs + fused hs.a_s
    k_gat_gather<<<nw(Nd), dim3(256), 0, stream>>>(rp, col, t1, sAs, sAd_src, bias,
                                                   out, Nd, relu, dvec, dout);
  };
  auto gcn = [&](const float* x, const int* rp, const int* col, const float* dis, int N,
                 int sidx, int layer, const float* b, const float* addin, float* out,
                 const float* dvec, float* dout) {
    gemm(x, sidx, layer, t1, nullptr, N, 0);
    k_gcn_gather<<<nw(N), dim3(256), 0, stream>>>(rp, col, dis, t1, addin, b, out, N,
                                                  dvec, dout);
  };
  auto sage = [&](const float* xsrc, const float* xself, const int* rp, const int* col,
                  int Nd, int sl, int sr, int layer, const float* bl, float* out) {
    gemm2g(xsrc, rp, col, sl, xself, sr, layer, out, bl, Nd);
  };

  // ---------- CD + MD, both layers ----------
  gat(x_md, x_cd, rp_comp, col_comp, N_MD, N_CD, 4, 0, WLv(24, 0),
      nullptr, 0, nullptr, nullptr, WLv(26, 0), acc, 0);
  gcn(x_cd, rp_cc, col_cc, dis_cc, N_CD, 6, 0, WLv(33, 0), acc, xcd1,
      wvall + 1 * 128, sAd2);
  gcn(x_md, rp_mm, col_mm, dis_mm, N_MD, 7, 0, WLv(35, 0), nullptr, xmd1,
      nullptr, nullptr);
  gat(xmd1, xcd1, rp_comp, col_comp, N_MD, N_CD, 4, 1, WLv(24, 1),
      sAd2, -1, nullptr, nullptr, WLv(26, 1), acc, 0);
  gcn(xcd1, rp_cc, col_cc, dis_cc, N_CD, 6, 1, WLv(33, 1), acc, acc,
      nullptr, nullptr);
  do_pool(acc, 0);
  gcn(xmd1, rp_mm, col_mm, dis_mm, N_MD, 7, 1, WLv(35, 1), nullptr, acc,
      nullptr, nullptr);
  do_pool(acc, 4);

  // ---------- SEQ ----------
  sage(x_cd, x_seq, rp_seq, col_seq, N_SEQ, 0, 1, 0, WLv(17, 0), xoth);
  sage(xcd1, xoth, rp_seq, col_seq, N_SEQ, 0, 1, 1, WLv(17, 1), acc);
  do_pool(acc, 1);
  // ---------- ANNO ----------
  sage(x_cd, x_anno, rp_anno, col_anno, N_ANNO, 2, 3, 0, WLv(20, 0), xoth);
  sage(xcd1, xoth, rp_anno, col_anno, N_ANNO, 2, 3, 1, WLv(20, 1), acc);
  do_pool(acc, 2);
  // ---------- RANGE ----------
  gat(x_cd, x_range, rp_range, col_range, N_CD, N_RANGE, 5, 0, WLv(29, 0),
      nullptr, 2, wvall + 3 * 128, sAd2, WLv(31, 0), xoth, 1);
  gat(xcd1, xoth, rp_range, col_range, N_CD, N_RANGE, 5, 1, WLv(29, 1),
      sAd2, -1, nullptr, nullptr, WLv(31, 1), acc, 1);
  do_pool(acc, 3);

  k_mlp<<<dim3(GNUM), dim3(128), 0, stream>>>(
      pool, fin(36), fin(37), fin(38), fin(39), (float*)d_out);
}

// Round 21
// 923.704 us; speedup vs baseline: 1.0696x; 1.0696x over previous
//
#include <hip/hip_runtime.h>

#define HD 128
#define GNUM 512
#define RPB 520
#define IDXCAP 512
#define TM 32

typedef __attribute__((ext_vector_type(8))) short short8v;
typedef __attribute__((ext_vector_type(4))) float f32x4;

// RNE split: a ~= hi + lo (both bf16)
__device__ __forceinline__ void split1(float a, short& h, short& l) {
  unsigned u = __float_as_uint(a);
  unsigned hb = (u + 0x7FFFu + ((u >> 16) & 1u)) & 0xFFFF0000u;
  h = (short)(hb >> 16);
  float rest = a - __uint_as_float(hb);
  unsigned u2 = __float_as_uint(rest);
  l = (short)((u2 + 0x7FFFu + ((u2 >> 16) & 1u)) >> 16);
}

// ============ W pre-split: fp32 [k][n] -> bf16 hi/lo TRANSPOSED [n][k] ============
struct WTab { const float* p[8]; };
__global__ __launch_bounds__(256) void k_split_w(WTab tab, short* __restrict__ whi,
                                                 short* __restrict__ wlo)
{
  int m = blockIdx.x >> 6;
  int i = (blockIdx.x & 63) * 256 + threadIdx.x;
  const float* W = tab.p[m >> 1] + (m & 1) * 16384;
  int k = i >> 7, n = i & 127;
  short h, l;
  split1(W[k * 128 + n], h, l);
  whi[m * 16384 + n * 128 + k] = h;
  wlo[m * 16384 + n * 128 + k] = l;
}

// ============ unified conv GEMM: C = AGG(A1)@W1 (+ A2@W2) (+bias,+addin,relu) =====
// mode 0: dense A1. mode 1: SAGE mean gather. mode 2: GCN (w_e=wsrc[c]*rowsc[r],
// self weight rowsc[r]^2). mode 3: GAT (w_e=exp(lrelu(wsrc[c]+rowsc[r]))/z).
// Optional fused FINAL-OUTPUT row-dots: adot[r]=out_row.avec, adot2[r]=out_row.avec2.
#define CF_LD 132
__global__ __launch_bounds__(256) void k_gemm_conv(
    const float* __restrict__ A1, const short* __restrict__ WH1, const short* __restrict__ WL1,
    const int* __restrict__ grp, const int* __restrict__ gcol, int mode,
    const float* __restrict__ wsrc, const float* __restrict__ rowsc,
    const float* __restrict__ A2, const short* __restrict__ WH2, const short* __restrict__ WL2,
    float* __restrict__ C, const float* __restrict__ bias, const float* addin,
    int N, int relu,
    const float* __restrict__ avec, float* __restrict__ adot,
    const float* __restrict__ avec2, float* __restrict__ adot2)
{
  __shared__ char smem[TM * 136 * 2 * 2];        // 17408 B
  __shared__ int idxbuf[IDXCAP];
  __shared__ float wbuf[IDXCAP];
  short* Ah = (short*)smem;
  short* Al = Ah + TM * 136;
  float* Cf = (float*)smem;

  const int t = threadIdx.x;
  const int row0 = blockIdx.x * TM;
  const int lane = t & 63, wid = t >> 6;
  const int g = lane >> 4, cn = lane & 15;
  const int colbase = wid * 32;

  f32x4 zero = {0.f, 0.f, 0.f, 0.f};
  f32x4 acc[2][2];
#pragma unroll
  for (int rt = 0; rt < 2; ++rt) { acc[rt][0] = zero; acc[rt][1] = zero; }

  auto storeAhl = [&](int row, int ln, float4 s) {
    short4 h, l;
    split1(s.x, h.x, l.x); split1(s.y, h.y, l.y);
    split1(s.z, h.z, l.z); split1(s.w, h.w, l.w);
    *(short4*)(Ah + row * 136 + ln * 4) = h;
    *(short4*)(Al + row * 136 + ln * 4) = l;
  };

  auto stageA = [&](const float* __restrict__ A) {
    const float4* A4 = (const float4*)(A + (size_t)row0 * 128);
#pragma unroll
    for (int i = 0; i < 4; ++i) {
      int f4 = t + i * 256;
      int row = f4 >> 5, c4 = f4 & 31;
      float4 v = make_float4(0.f, 0.f, 0.f, 0.f);
      if (row0 + row < N) v = A4[f4];
      storeAhl(row, c4, v);
    }
  };

  auto getcw = [&](int e, int e_lo, int& c, float& w) {
    int off = e - e_lo;
    if (off < IDXCAP) { c = idxbuf[off]; w = wbuf[off]; }
    else { c = gcol[e]; w = wsrc ? wsrc[c] : 0.f; }
  };

  // mode 1: mean; mode 2: gcn weighted + self; mode 3: gat softmax
  auto stage_gather = [&](const float* __restrict__ X, int e_lo) {
#pragma unroll
    for (int i = 0; i < 4; ++i) {
      int f4 = t + i * 256;
      int row = f4 >> 5, ln = f4 & 31;
      int r = row0 + row;
      float4 s = make_float4(0.f, 0.f, 0.f, 0.f);
      int e0 = 0, e1 = 0;
      float rs = 0.f;
      if (r < N) {
        e0 = grp[r]; e1 = grp[r + 1];
        if (mode >= 2) rs = rowsc[r];
      }
      float z = 0.f;
      if (mode == 2 && r < N) {          // self term: rr * x_r (contiguous)
        float4 xs_ = *(const float4*)(X + (size_t)r * 128 + ln * 4);
        float rr = rs * rs;
        s.x = rr * xs_.x; s.y = rr * xs_.y; s.z = rr * xs_.z; s.w = rr * xs_.w;
      }
      int e = e0;
      for (; e + 1 < e1; e += 2) {
        int c0, c1; float w0, w1;
        getcw(e, e_lo, c0, w0);
        getcw(e + 1, e_lo, c1, w1);
        float p0, p1;
        if (mode == 3) {
          float v0 = w0 + rs; v0 = v0 > 0.f ? v0 : 0.2f * v0;
          float v1 = w1 + rs; v1 = v1 > 0.f ? v1 : 0.2f * v1;
          p0 = __expf(v0); p1 = __expf(v1); z += p0 + p1;
        } else if (mode == 2) { p0 = w0 * rs; p1 = w1 * rs; }
        else { p0 = 1.f; p1 = 1.f; }
        float4 a = *(const float4*)(X + (size_t)c0 * 128 + ln * 4);
        float4 b = *(const float4*)(X + (size_t)c1 * 128 + ln * 4);
        s.x += p0 * a.x + p1 * b.x; s.y += p0 * a.y + p1 * b.y;
        s.z += p0 * a.z + p1 * b.z; s.w += p0 * a.w + p1 * b.w;
      }
      if (e < e1) {
        int c; float w;
        getcw(e, e_lo, c, w);
        float p;
        if (mode == 3) {
          float v = w + rs; v = v > 0.f ? v : 0.2f * v;
          p = __expf(v); z += p;
        } else if (mode == 2) p = w * rs;
        else p = 1.f;
        float4 a = *(const float4*)(X + (size_t)c * 128 + ln * 4);
        s.x += p * a.x; s.y += p * a.y; s.z += p * a.z; s.w += p * a.w;
      }
      if (mode == 1) {
        float inv = 1.f / fmaxf((float)(e1 - e0), 1.f);
        s.x *= inv; s.y *= inv; s.z *= inv; s.w *= inv;
      } else if (mode == 3) {
        float inv = (e1 > e0) ? 1.f / z : 0.f;
        s.x *= inv; s.y *= inv; s.z *= inv; s.w *= inv;
      }
      storeAhl(row, ln, s);
    }
  };

  auto accum = [&](const short* __restrict__ WH, const short* __restrict__ WL) {
#pragma unroll
    for (int kg = 0; kg < 4; ++kg) {
      short8v bhi[2], blo[2];
#pragma unroll
      for (int ct = 0; ct < 2; ++ct) {
        size_t o = (size_t)(colbase + ct * 16 + cn) * 128 + kg * 32 + g * 8;
        bhi[ct] = *(const short8v*)(WH + o);
        blo[ct] = *(const short8v*)(WL + o);
      }
#pragma unroll
      for (int rt = 0; rt < 2; ++rt) {
        const int ao = (rt * 16 + cn) * 136 + kg * 32 + g * 8;
        const short8v ah = *(const short8v*)(Ah + ao);
        const short8v al = *(const short8v*)(Al + ao);
#pragma unroll
        for (int ct = 0; ct < 2; ++ct) {
          acc[rt][ct] = __builtin_amdgcn_mfma_f32_16x16x32_bf16(ah, bhi[ct], acc[rt][ct], 0, 0, 0);
          acc[rt][ct] = __builtin_amdgcn_mfma_f32_16x16x32_bf16(al, bhi[ct], acc[rt][ct], 0, 0, 0);
          acc[rt][ct] = __builtin_amdgcn_mfma_f32_16x16x32_bf16(ah, blo[ct], acc[rt][ct], 0, 0, 0);
        }
      }
    }
  };

  if (mode != 0) {
    const int row_end = min(row0 + TM, N);
    const int e_lo = grp[row0];
    const int cnt = min(grp[row_end] - e_lo, IDXCAP);
    for (int k = t; k < cnt; k += 256) {
      int idx = gcol[e_lo + k];
      idxbuf[k] = idx;
      if (wsrc) wbuf[k] = wsrc[idx];
    }
    __syncthreads();
    stage_gather(A1, e_lo);
  } else {
    stageA(A1);
  }
  __syncthreads();
  accum(WH1, WL1);
  if (A2) {
    __syncthreads();
    stageA(A2);
    __syncthreads();
    accum(WH2, WL2);
  }
  __syncthreads();

  // acc -> LDS C-tile (C/D layout col=lane&15, row=(lane>>4)*4+reg)
#pragma unroll
  for (int rt = 0; rt < 2; ++rt)
#pragma unroll
    for (int ct = 0; ct < 2; ++ct)
#pragma unroll
      for (int r = 0; r < 4; ++r)
        Cf[(rt * 16 + g * 4 + r) * CF_LD + colbase + ct * 16 + cn] = acc[rt][ct][r];
  __syncthreads();

  float4* C4 = (float4*)(C + (size_t)row0 * 128);
#pragma unroll
  for (int i = 0; i < 4; ++i) {
    int f4 = t + i * 256;
    int row = f4 >> 5, c4 = f4 & 31;
    if (row0 + row < N) {
      float4 v = *(const float4*)(Cf + row * CF_LD + c4 * 4);
      if (bias) {
        float4 bv = *(const float4*)(bias + c4 * 4);
        v.x += bv.x; v.y += bv.y; v.z += bv.z; v.w += bv.w;
      }
      if (addin) {
        float4 av = *(const float4*)(addin + (size_t)(row0 + row) * 128 + c4 * 4);
        v.x += av.x; v.y += av.y; v.z += av.z; v.w += av.w;
      }
      if (relu) {
        v.x = fmaxf(v.x, 0.f); v.y = fmaxf(v.y, 0.f);
        v.z = fmaxf(v.z, 0.f); v.w = fmaxf(v.w, 0.f);
      }
      C4[f4] = v;
      // fused final-output dots (reduce over the row's 32 chunk-threads)
      if (avec) {
        float4 av = *(const float4*)(avec + c4 * 4);
        float p = v.x * av.x + v.y * av.y + v.z * av.z + v.w * av.w;
#pragma unroll
        for (int o = 1; o < 32; o <<= 1) p += __shfl_xor(p, o);
        if (c4 == 0) adot[row0 + row] = p;
      }
      if (avec2) {
        float4 av = *(const float4*)(avec2 + c4 * 4);
        float p = v.x * av.x + v.y * av.y + v.z * av.z + v.w * av.w;
#pragma unroll
        for (int o = 1; o < 32; o <<= 1) p += __shfl_xor(p, o);
        if (c4 == 0) adot2[row0 + row] = p;
      }
    }
  }
}

// ======================= row dots (one wave / node) =======================
__global__ void k_rowdot(const float* __restrict__ x, const float* __restrict__ a,
                         float* __restrict__ out, int N)
{
  int wid = blockIdx.x * 4 + (threadIdx.x >> 6);
  int lane = threadIdx.x & 63;
  if (wid >= N) return;
  float2 xv = ((const float2*)x)[(size_t)wid * 64 + lane];
  float2 av = ((const float2*)a)[lane];
  float v = fmaf(xv.y, av.y, xv.x * av.x);
#pragma unroll
  for (int o = 32; o > 0; o >>= 1) v += __shfl_down(v, o);
  if (lane == 0) out[wid] = v;
}

__global__ void k_rowdot2(const float* __restrict__ x, const float* __restrict__ a1,
                          const float* __restrict__ a2, float* __restrict__ o1,
                          float* __restrict__ o2, int N)
{
  int wid = blockIdx.x * 4 + (threadIdx.x >> 6);
  int lane = threadIdx.x & 63;
  if (wid >= N) return;
  float2 xv = ((const float2*)x)[(size_t)wid * 64 + lane];
  float2 av1 = ((const float2*)a1)[lane];
  float2 av2 = ((const float2*)a2)[lane];
  float v1 = fmaf(xv.y, av1.y, xv.x * av1.x);
  float v2 = fmaf(xv.y, av2.y, xv.x * av2.x);
#pragma unroll
  for (int o = 32; o > 0; o >>= 1) { v1 += __shfl_down(v1, o); v2 += __shfl_down(v2, o); }
  if (lane == 0) { o1[wid] = v1; o2[wid] = v2; }
}

// ================= batched matvec: wv[m][i] = sum_j W_m[i,j]*a_m[j] ==============
struct MTab { const float* W[8]; const float* a[8]; };
__global__ __launch_bounds__(128) void k_matvec8(MTab tb, float* __restrict__ wv)
{
  __shared__ float as[128];
  int m = blockIdx.x, i = threadIdx.x;
  as[i] = tb.a[m][i];
  __syncthreads();
  const float* W = tb.W[m];
  float v = 0.f;
  for (int j = 0; j < 128; ++j) v = fmaf(W[i * 128 + j], as[j], v);
  wv[m * 128 + i] = v;
}

// ======================= batched CSR build =======================
struct HTab { const int* key[6]; int* cnt[6]; unsigned short* rank[6]; int bo[7]; int n[6]; };
__global__ void k_hist_rank_all(HTab tb) {
  int bi = blockIdx.x, ty = 0;
  while (ty < 5 && bi >= tb.bo[ty + 1]) ++ty;
  int i = (bi - tb.bo[ty]) * 256 + threadIdx.x;
  if (i < tb.n[ty])
    tb.rank[ty][i] = (unsigned short)atomicAdd(&tb.cnt[ty][tb.key[ty][i]], 1);
}

struct FTab { const int* es[6]; const int* ed[6]; const int* rp[6];
              const unsigned short* rank[6]; int* col[6]; int bo[7]; int n[6]; };
__global__ void k_fill_all(FTab tb) {
  int bi = blockIdx.x, ty = 0;
  while (ty < 5 && bi >= tb.bo[ty + 1]) ++ty;
  int e = (bi - tb.bo[ty]) * 256 + threadIdx.x;
  if (e >= tb.n[ty]) return;
  int p = tb.rp[ty][tb.ed[ty][e]] + (int)tb.rank[ty][e];
  tb.col[ty][p] = tb.es[ty][e];
}

struct STab { int* rp[6]; int* bs[6]; int n[6]; int bo[7]; };

__global__ __launch_bounds__(256) void k_scan_partial_all(STab tb) {
  __shared__ int red[256];
  int bi = blockIdx.x, ty = 0;
  while (ty < 5 && bi >= tb.bo[ty + 1]) ++ty;
  int lb = bi - tb.bo[ty];
  const int* rp = tb.rp[ty];
  const int N = tb.n[ty];
  const int t = threadIdx.x, base = lb * 4096;
  int s = 0;
  for (int i = t; i < 4096; i += 256) {
    int idx = base + i;
    if (idx < N) s += rp[idx];
  }
  red[t] = s;
  __syncthreads();
  for (int ofs = 128; ofs > 0; ofs >>= 1) {
    if (t < ofs) red[t] += red[t + ofs];
    __syncthreads();
  }
  if (t == 0) tb.bs[ty][lb] = red[0];
}

__global__ __launch_bounds__(256) void k_scan_bsums_all(STab tb) {
  __shared__ int sh[256];
  const int ty = blockIdx.x;
  const int nb = (tb.n[ty] + 4095) / 4096;
  const int t = threadIdx.x;
  int v = (t < nb) ? tb.bs[ty][t] : 0;
  sh[t] = v;
  __syncthreads();
  for (int ofs = 1; ofs < 256; ofs <<= 1) {
    int u = (t >= ofs) ? sh[t - ofs] : 0;
    __syncthreads();
    sh[t] += u;
    __syncthreads();
  }
  if (t < nb) tb.bs[ty][t] = sh[t] - v;
  if (t == 255) tb.rp[ty][tb.n[ty]] = sh[255];
}

__global__ __launch_bounds__(256) void k_scan_final_all(STab tb) {
  __shared__ int sh[4096 + 256];
  __shared__ int tsum[256];
  int bi = blockIdx.x, ty = 0;
  while (ty < 5 && bi >= tb.bo[ty + 1]) ++ty;
  int lb = bi - tb.bo[ty];
  int* rp = tb.rp[ty];
  const int N = tb.n[ty];
  const int t = threadIdx.x, base = lb * 4096;
  auto mp = [](int i) { return i + (i >> 4); };
#pragma unroll
  for (int i = 0; i < 16; ++i) {
    int idx = base + i * 256 + t;
    sh[mp(i * 256 + t)] = (idx < N) ? rp[idx] : 0;
  }
  __syncthreads();
  int s = 0;
#pragma unroll
  for (int j = 0; j < 16; ++j) s += sh[mp(t * 16 + j)];
  tsum[t] = s;
  __syncthreads();
  for (int ofs = 1; ofs < 256; ofs <<= 1) {
    int u = (t >= ofs) ? tsum[t - ofs] : 0;
    __syncthreads();
    tsum[t] += u;
    __syncthreads();
  }
  int pre = tsum[t] - s + tb.bs[ty][lb];
#pragma unroll
  for (int j = 0; j < 16; ++j) {
    int v = sh[mp(t * 16 + j)];
    sh[mp(t * 16 + j)] = pre;
    pre += v;
  }
  __syncthreads();
#pragma unroll
  for (int i = 0; i < 16; ++i) {
    int idx = base + i * 256 + t;
    if (idx < N) rp[idx] = sh[mp(i * 256 + t)];
  }
}

// ---- run-pointers for SORTED batch vectors via binary search ----
struct BTab { const int* b[5]; int n[5]; };
__global__ __launch_bounds__(512) void k_runptr(BTab tb, int* __restrict__ rpb_all) {
  const int ty = blockIdx.x;
  const int* b = tb.b[ty];
  const int N = tb.n[ty];
  const int t = threadIdx.x;
  int lo = 0, hi = N;
  while (lo < hi) {
    int mid = (lo + hi) >> 1;
    if (b[mid] < t) lo = mid + 1; else hi = mid;
  }
  rpb_all[ty * RPB + t] = lo;
  if (t == 0) rpb_all[ty * RPB + GNUM] = N;
}

struct DTab { const int* rp[2]; float* dis[2]; int n[2]; int bo[3]; };
__global__ void k_dis2(DTab tb) {
  int bi = blockIdx.x, ty = (bi >= tb.bo[1]) ? 1 : 0;
  int n = (bi - tb.bo[ty]) * 256 + threadIdx.x;
  if (n < tb.n[ty]) tb.dis[ty][n] = rsqrtf((float)(tb.rp[ty][n + 1] - tb.rp[ty][n]) + 1.f);
}

// ============ segment pooling: one block per graph, contiguous rows ============
__global__ __launch_bounds__(256) void k_pool_seg(
    const float* __restrict__ x, const int* __restrict__ rpb,
    float* __restrict__ pool, int col_off)
{
  __shared__ float2 red2[4][64];
  const int g = blockIdx.x;
  const int t = threadIdx.x, w = t >> 6, lane = t & 63;
  const int n0 = rpb[g], n1 = rpb[g + 1];
  const float2* x2 = (const float2*)x;
  float a0 = 0.f, a1 = 0.f, b0 = 0.f, b1 = 0.f;
  int n = n0 + w;
  for (; n + 4 < n1; n += 8) {
    float2 vA = x2[(size_t)n * 64 + lane];
    float2 vB = x2[(size_t)(n + 4) * 64 + lane];
    a0 += vA.x; a1 += vA.y; b0 += vB.x; b1 += vB.y;
  }
  if (n < n1) { float2 vA = x2[(size_t)n * 64 + lane]; a0 += vA.x; a1 += vA.y; }
  red2[w][lane] = make_float2(a0 + b0, a1 + b1);
  __syncthreads();
  if (t < 64) {
    float2 r0 = red2[0][t], r1 = red2[1][t], r2 = red2[2][t], r3 = red2[3][t];
    float inv = 1.f / fmaxf((float)(n1 - n0), 1.f);
    ((float2*)(pool + (size_t)g * 640 + col_off))[t] =
        make_float2((r0.x + r1.x + r2.x + r3.x) * inv,
                    (r0.y + r1.y + r2.y + r3.y) * inv);
  }
}

// ======================= final MLP (one block per graph) =======================
__global__ void k_mlp(const float* __restrict__ pool,
                      const float* __restrict__ W1, const float* __restrict__ b1,
                      const float* __restrict__ W2, const float* __restrict__ b2,
                      float* __restrict__ out)
{
  __shared__ float emb[640];
  __shared__ float red[128];
  const int g = blockIdx.x, t = threadIdx.x;
  for (int i = t; i < 640; i += 128) emb[i] = pool[(size_t)g * 640 + i];
  __syncthreads();
  float acc = b1[t];
  for (int i = 0; i < 640; ++i) acc = fmaf(emb[i], W1[i * 128 + t], acc);
  float h = fmaxf(acc, 0.f);
  red[t] = h * W2[t];
  __syncthreads();
  for (int s = 64; s > 0; s >>= 1) {
    if (t < s) red[t] += red[t + s];
    __syncthreads();
  }
  if (t == 0) out[g] = red[0] + b2[0];
}

// ======================= host =======================
extern "C" void kernel_launch(void* const* d_in, const int* in_sizes, int n_in,
                              void* d_out, int out_size, void* d_ws, size_t ws_size,
                              hipStream_t stream)
{
  auto fin = [&](int i) { return (const float*)d_in[i]; };
  auto iin = [&](int i) { return (const int*)d_in[i]; };

  const float *x_cd = fin(0), *x_seq = fin(1), *x_anno = fin(2), *x_range = fin(3), *x_md = fin(4);
  const int *ei_seq = iin(5), *ei_anno = iin(6), *ei_range = iin(7),
            *ei_comp = iin(8), *ei_cc = iin(9), *ei_mm = iin(10);
  const int *b_cd = iin(11), *b_seq = iin(12), *b_anno = iin(13), *b_range = iin(14), *b_md = iin(15);

  const int N_CD = in_sizes[0] / HD, N_SEQ = in_sizes[1] / HD, N_ANNO = in_sizes[2] / HD,
            N_RANGE = in_sizes[3] / HD, N_MD = in_sizes[4] / HD;
  const int E_seq = in_sizes[5] / 2, E_anno = in_sizes[6] / 2, E_range = in_sizes[7] / 2,
            E_comp = in_sizes[8] / 2, E_cc = in_sizes[9] / 2, E_mm = in_sizes[10] / 2;
  const int N_OTH = max(max(N_SEQ, N_ANNO), N_RANGE);

  auto WLm = [&](int i, int l) { return fin(i) + (size_t)l * HD * HD; };
  auto WLv = [&](int i, int l) { return fin(i) + (size_t)l * HD; };

  // ---- workspace layout ----
  float* ws = (float*)d_ws;
  size_t off = 0;
  auto alloc = [&](size_t n) { float* p = ws + off; off += (n + 3) & ~(size_t)3; return p; };
  float* xcd1 = alloc((size_t)N_CD * HD);
  float* xmd1 = alloc((size_t)N_MD * HD);
  float* xoth = alloc((size_t)N_OTH * HD);
  float* acc  = alloc((size_t)N_CD * HD);
  float* t1   = alloc((size_t)N_CD * HD);
  float* sA = alloc((size_t)N_CD);   // comp sAs (L0 md / L1 md)
  float* sB = alloc((size_t)N_CD);   // comp sAd (L0 cd / L1 cd)
  float* sC = alloc((size_t)N_CD);   // range L0 sAs (cd)
  float* sD = alloc((size_t)N_CD);   // range L0 sAd (range)
  float* sE = alloc((size_t)N_CD);   // range L1 sAs (cd)
  float* sF = alloc((size_t)N_CD);   // range L1 sAd (range)
  float* dis_cc = alloc((size_t)N_CD);
  float* dis_mm = alloc((size_t)N_MD);
  float* wv8 = alloc(8 * HD);
  float* pool = alloc((size_t)GNUM * 5 * HD);
  short* whi = (short*)(ws + off); off += (size_t)16 * 16384 / 2;
  short* wlo = (short*)(ws + off); off += (size_t)16 * 16384 / 2;
  auto alloci = [&](size_t n) { int* p = (int*)(ws + off); off += (n + 3) & ~(size_t)3; return p; };
  int* bsall = alloci(6 * 256);
  int* rpb_all = alloci(5 * RPB);
  int Nds[6] = {N_SEQ, N_ANNO, N_RANGE, N_CD, N_CD, N_MD};
  int Es[6]  = {E_seq, E_anno, E_range, E_comp, E_cc, E_mm};
  int* rps[6];
  int* rp0 = alloci(0);
  { size_t tot = 0; for (int i = 0; i < 6; ++i) tot += (size_t)Nds[i] + 1;
    int* p = alloci(tot); rp0 = p;
    for (int i = 0; i < 6; ++i) { rps[i] = p; p += Nds[i] + 1; } }
  size_t rp_tot_bytes = 0; for (int i = 0; i < 6; ++i) rp_tot_bytes += ((size_t)Nds[i] + 1) * 4;
  unsigned short* ranks[6];
  for (int i = 0; i < 6; ++i) ranks[i] = (unsigned short*)alloci(((size_t)Es[i] + 1) / 2);
  int* cols[6];  for (int i = 0; i < 6; ++i) cols[i] = alloci((size_t)Es[i]);
  (void)n_in;

  if (off * sizeof(float) > ws_size) {
    hipMemsetAsync(d_out, 0, (size_t)out_size * sizeof(float), stream);
    return;
  }

  auto ew = [&](size_t elems) { return dim3((unsigned)((elems + 255) / 256)); };
  auto nw = [&](int N) { return dim3((unsigned)((N + 3) / 4)); };

  // ---- pre-split all GEMM weights (slots: 0:16 1:18 2:19 3:21 4:22 5:27 6:32 7:34)
  WTab tab;
  tab.p[0] = fin(16); tab.p[1] = fin(18); tab.p[2] = fin(19); tab.p[3] = fin(21);
  tab.p[4] = fin(22); tab.p[5] = fin(27); tab.p[6] = fin(32); tab.p[7] = fin(34);
  k_split_w<<<dim3(1024), dim3(256), 0, stream>>>(tab, whi, wlo);

  // ---- 8 GAT matvecs: s/d for comp L0,L1 and range L0,L1 ----
  MTab mt;
  mt.W[0] = WLm(22, 0); mt.a[0] = WLv(24, 0);   // Ws comp0 @ as0
  mt.W[1] = WLm(23, 0); mt.a[1] = WLv(25, 0);   // Wd comp0 @ ad0
  mt.W[2] = WLm(22, 1); mt.a[2] = WLv(24, 1);   // Ws comp1
  mt.W[3] = WLm(23, 1); mt.a[3] = WLv(25, 1);   // Wd comp1
  mt.W[4] = WLm(27, 0); mt.a[4] = WLv(29, 0);   // Ws range0
  mt.W[5] = WLm(28, 0); mt.a[5] = WLv(30, 0);   // Wd range0
  mt.W[6] = WLm(27, 1); mt.a[6] = WLv(29, 1);   // Ws range1
  mt.W[7] = WLm(28, 1); mt.a[7] = WLv(30, 1);   // Wd range1
  k_matvec8<<<dim3(8), dim3(128), 0, stream>>>(mt, wv8);

  // ---- input-side attention scalars ----
  k_rowdot<<<nw(N_MD), dim3(256), 0, stream>>>(x_md, wv8 + 0 * 128, sA, N_MD);       // comp0 sAs
  k_rowdot2<<<nw(N_CD), dim3(256), 0, stream>>>(x_cd, wv8 + 1 * 128, wv8 + 4 * 128,
                                                sB, sC, N_CD);                        // comp0 sAd, range0 sAs
  k_rowdot<<<nw(N_RANGE), dim3(256), 0, stream>>>(x_range, wv8 + 5 * 128, sD, N_RANGE); // range0 sAd

  // ---- run-pointers for sorted batch vectors ----
  {
    BTab bt;
    bt.b[0] = b_cd; bt.n[0] = N_CD;  bt.b[1] = b_seq; bt.n[1] = N_SEQ;
    bt.b[2] = b_anno; bt.n[2] = N_ANNO;  bt.b[3] = b_range; bt.n[3] = N_RANGE;
    bt.b[4] = b_md; bt.n[4] = N_MD;
    k_runptr<<<dim3(5), dim3(512), 0, stream>>>(bt, rpb_all);
  }

  // ---- batched CSR build ----
  const int* ess[6] = {ei_seq, ei_anno, ei_range, ei_comp, ei_cc, ei_mm};
  const int* eds[6] = {ei_seq + E_seq, ei_anno + E_anno, ei_range + E_range,
                       ei_comp + E_comp, ei_cc + E_cc, ei_mm + E_mm};
  hipMemsetAsync(rp0, 0, rp_tot_bytes, stream);
  {
    HTab ht; int b = 0;
    for (int i = 0; i < 6; ++i) {
      ht.key[i] = eds[i]; ht.cnt[i] = rps[i]; ht.rank[i] = ranks[i];
      ht.bo[i] = b; b += (Es[i] + 255) / 256; ht.n[i] = Es[i];
    }
    ht.bo[6] = b;
    k_hist_rank_all<<<dim3(b), dim3(256), 0, stream>>>(ht);
  }
  {
    STab st; int b = 0;
    for (int i = 0; i < 6; ++i) {
      st.rp[i] = rps[i]; st.bs[i] = bsall + i * 256;
      st.n[i] = Nds[i]; st.bo[i] = b; b += (Nds[i] + 4095) / 4096;
    }
    st.bo[6] = b;
    k_scan_partial_all<<<dim3(b), dim3(256), 0, stream>>>(st);
    k_scan_bsums_all<<<dim3(6), dim3(256), 0, stream>>>(st);
    k_scan_final_all<<<dim3(b), dim3(256), 0, stream>>>(st);
  }
  {
    FTab ft; int b = 0;
    for (int i = 0; i < 6; ++i) {
      ft.es[i] = ess[i]; ft.ed[i] = eds[i]; ft.rp[i] = rps[i]; ft.rank[i] = ranks[i];
      ft.col[i] = cols[i]; ft.bo[i] = b; b += (Es[i] + 255) / 256; ft.n[i] = Es[i];
    }
    ft.bo[6] = b;
    k_fill_all<<<dim3(b), dim3(256), 0, stream>>>(ft);
  }
  int *rp_seq = rps[0], *rp_anno = rps[1], *rp_range = rps[2],
      *rp_comp = rps[3], *rp_cc = rps[4], *rp_mm = rps[5];
  int *col_seq = cols[0], *col_anno = cols[1], *col_range = cols[2],
      *col_comp = cols[3], *col_cc = cols[4], *col_mm = cols[5];
  {
    DTab dt;
    dt.rp[0] = rp_cc; dt.dis[0] = dis_cc; dt.n[0] = N_CD;
    dt.rp[1] = rp_mm; dt.dis[1] = dis_mm; dt.n[1] = N_MD;
    dt.bo[0] = 0; dt.bo[1] = (N_CD + 255) / 256;
    dt.bo[2] = dt.bo[1] + (N_MD + 255) / 256;
    k_dis2<<<dim3(dt.bo[2]), dim3(256), 0, stream>>>(dt);
  }

  auto WHp = [&](int sidx, int layer) { return whi + (size_t)(sidx * 2 + layer) * 16384; };
  auto WLp = [&](int sidx, int layer) { return wlo + (size_t)(sidx * 2 + layer) * 16384; };

  auto conv = [&](int mode, const float* A1, int sidx, int layer,
                  const int* grp, const int* gcol,
                  const float* wsrc, const float* rowsc,
                  const float* A2, int sidx2,
                  float* C, const float* bias, const float* addin, int N, int relu,
                  const float* avec, float* adot, const float* avec2, float* adot2) {
    k_gemm_conv<<<dim3((N + TM - 1) / TM), dim3(256), 0, stream>>>(
        A1, WHp(sidx, layer), WLp(sidx, layer), grp, gcol, mode, wsrc, rowsc,
        A2, A2 ? WHp(sidx2, layer) : nullptr, A2 ? WLp(sidx2, layer) : nullptr,
        C, bias, addin, N, relu, avec, adot, avec2, adot2);
  };
  auto do_pool = [&](const float* x, int type) {
    k_pool_seg<<<dim3(GNUM), dim3(256), 0, stream>>>(x, rpb_all + type * RPB, pool, type * HD);
  };

  // ---------- CD + MD, both layers (all fused gather-GEMMs) ----------
  // comp L0 GAT (dst=CD, src=MD): out -> acc (bias, no relu)
  conv(3, x_md, 4, 0, rp_comp, col_comp, sA, sB, nullptr, 0,
       acc, WLv(26, 0), nullptr, N_CD, 0, nullptr, nullptr, nullptr, nullptr);
  // cc L1 GCN -> xcd1; fused dots: comp1 sAd (wv3) -> sB, range1 sAs (wv6) -> sE
  conv(2, x_cd, 6, 0, rp_cc, col_cc, dis_cc, dis_cc, nullptr, 0,
       xcd1, WLv(33, 0), acc, N_CD, 1, wv8 + 3 * 128, sB, wv8 + 6 * 128, sE);
  // mm L1 GCN -> xmd1; fused dot: comp1 sAs (wv2) -> sA
  conv(2, x_md, 7, 0, rp_mm, col_mm, dis_mm, dis_mm, nullptr, 0,
       xmd1, WLv(35, 0), nullptr, N_MD, 1, wv8 + 2 * 128, sA, nullptr, nullptr);
  // comp L1 GAT -> acc
  conv(3, xmd1, 4, 1, rp_comp, col_comp, sA, sB, nullptr, 0,
       acc, WLv(26, 1), nullptr, N_CD, 0, nullptr, nullptr, nullptr, nullptr);
  // cc L2 GCN -> acc (addin = acc, aliasing safe)
  conv(2, xcd1, 6, 1, rp_cc, col_cc, dis_cc, dis_cc, nullptr, 0,
       acc, WLv(33, 1), acc, N_CD, 1, nullptr, nullptr, nullptr, nullptr);
  do_pool(acc, 0);
  // mm L2 GCN -> acc
  conv(2, xmd1, 7, 1, rp_mm, col_mm, dis_mm, dis_mm, nullptr, 0,
       acc, WLv(35, 1), nullptr, N_MD, 1, nullptr, nullptr, nullptr, nullptr);
  do_pool(acc, 4);

  // ---------- SEQ (SAGE) ----------
  conv(1, x_cd, 0, 0, rp_seq, col_seq, nullptr, nullptr, x_seq, 1,
       xoth, WLv(17, 0), nullptr, N_SEQ, 1, nullptr, nullptr, nullptr, nullptr);
  conv(1, xcd1, 0, 1, rp_seq, col_seq, nullptr, nullptr, xoth, 1,
       acc, WLv(17, 1), nullptr, N_SEQ, 1, nullptr, nullptr, nullptr, nullptr);
  do_pool(acc, 1);
  // ---------- ANNO (SAGE) ----------
  conv(1, x_cd, 2, 0, rp_anno, col_anno, nullptr, nullptr, x_anno, 3,
       t1, WLv(20, 0), nullptr, N_ANNO, 1, nullptr, nullptr, nullptr, nullptr);
  conv(1, xcd1, 2, 1, rp_anno, col_anno, nullptr, nullptr, t1, 3,
       acc, WLv(20, 1), nullptr, N_ANNO, 1, nullptr, nullptr, nullptr, nullptr);
  do_pool(acc, 2);
  // ---------- RANGE (GAT) ----------
  // L0 -> xoth; fused dot: range1 sAd (wv7) -> sF
  conv(3, x_cd, 5, 0, rp_range, col_range, sC, sD, nullptr, 0,
       xoth, WLv(31, 0), nullptr, N_RANGE, 1, wv8 + 7 * 128, sF, nullptr, nullptr);
  // L1 -> acc
  conv(3, xcd1, 5, 1, rp_range, col_range, sE, sF, nullptr, 0,
       acc, WLv(31, 1), nullptr, N_RANGE, 1, nullptr, nullptr, nullptr, nullptr);
  do_pool(acc, 3);

  k_mlp<<<dim3(GNUM), dim3(128), 0, stream>>>(
      pool, fin(36), fin(37), fin(38), fin(39), (float*)d_out);
}

// Round 22
// 884.398 us; speedup vs baseline: 1.1172x; 1.0444x over previous
//
#include <hip/hip_runtime.h>

#define HD 128
#define GNUM 512
#define RPB 520
#define IDXCAP 512
#define TM 32

typedef __attribute__((ext_vector_type(8))) short short8v;
typedef __attribute__((ext_vector_type(4))) float f32x4;

// RNE split: a ~= hi + lo (both bf16)
__device__ __forceinline__ void split1(float a, short& h, short& l) {
  unsigned u = __float_as_uint(a);
  unsigned hb = (u + 0x7FFFu + ((u >> 16) & 1u)) & 0xFFFF0000u;
  h = (short)(hb >> 16);
  float rest = a - __uint_as_float(hb);
  unsigned u2 = __float_as_uint(rest);
  l = (short)((u2 + 0x7FFFu + ((u2 >> 16) & 1u)) >> 16);
}

// ============ W pre-split: fp32 [k][n] -> bf16 hi/lo TRANSPOSED [n][k] ============
struct WTab { const float* p[8]; };
__global__ __launch_bounds__(256) void k_split_w(WTab tab, short* __restrict__ whi,
                                                 short* __restrict__ wlo)
{
  int m = blockIdx.x >> 6;
  int i = (blockIdx.x & 63) * 256 + threadIdx.x;
  const float* W = tab.p[m >> 1] + (m & 1) * 16384;
  int k = i >> 7, n = i & 127;
  short h, l;
  split1(W[k * 128 + n], h, l);
  whi[m * 16384 + n * 128 + k] = h;
  wlo[m * 16384 + n * 128 + k] = l;
}

// ============ unified conv GEMM: C = AGG0(A0)@W0 (+ AGG1(A1)@W1) (+biases,relu) ===
// per-op mode: 0 dense, 1 SAGE mean, 2 GCN (w=wsrc[c]*rowsc[r] + self rowsc^2),
// 3 GAT softmax (w=exp(lrelu(wsrc[c]+rowsc[r]))/z).
// Optional fused FINAL-OUTPUT row-dots.
struct COp {
  const float* A; const short* WH; const short* WL;
  const int* grp; const int* gcol;
  const float* wsrc; const float* rowsc; int mode;
};
#define CF_LD 132
__global__ __launch_bounds__(256) void k_gemm_conv(
    COp o0, COp o1, int hasO1,
    float* __restrict__ C, const float* __restrict__ bias, const float* __restrict__ bias2,
    const float* addin, int N, int relu,
    const float* __restrict__ avec, float* __restrict__ adot,
    const float* __restrict__ avec2, float* __restrict__ adot2)
{
  __shared__ char smem[TM * 136 * 2 * 2];        // 17408 B
  __shared__ int idxbuf[IDXCAP];
  __shared__ float wbuf[IDXCAP];
  short* Ah = (short*)smem;
  short* Al = Ah + TM * 136;
  float* Cf = (float*)smem;

  const int t = threadIdx.x;
  const int row0 = blockIdx.x * TM;
  const int lane = t & 63, wid = t >> 6;
  const int g = lane >> 4, cn = lane & 15;
  const int colbase = wid * 32;

  f32x4 zero = {0.f, 0.f, 0.f, 0.f};
  f32x4 acc[2][2];
#pragma unroll
  for (int rt = 0; rt < 2; ++rt) { acc[rt][0] = zero; acc[rt][1] = zero; }

  auto storeAhl = [&](int row, int ln, float4 s) {
    short4 h, l;
    split1(s.x, h.x, l.x); split1(s.y, h.y, l.y);
    split1(s.z, h.z, l.z); split1(s.w, h.w, l.w);
    *(short4*)(Ah + row * 136 + ln * 4) = h;
    *(short4*)(Al + row * 136 + ln * 4) = l;
  };

  auto stageA = [&](const float* __restrict__ A) {
#pragma unroll
    for (int i = 0; i < 4; ++i) {
      int f4 = t + i * 256;
      int row = f4 >> 5, c4 = f4 & 31;
      float4 v = make_float4(0.f, 0.f, 0.f, 0.f);
      if (row0 + row < N) v = ((const float4*)(A + (size_t)row0 * 128))[f4];
      storeAhl(row, c4, v);
    }
  };

  auto prefetch = [&](const COp& op) {
    const int row_end = min(row0 + TM, N);
    const int e_lo = op.grp[row0];
    const int cnt = min(op.grp[row_end] - e_lo, IDXCAP);
    for (int k = t; k < cnt; k += 256) {
      int idx = op.gcol[e_lo + k];
      idxbuf[k] = idx;
      if (op.wsrc) wbuf[k] = op.wsrc[idx];
    }
  };

  auto stage_gather = [&](const COp& op) {
    const int e_lo = op.grp[row0];
    const int mode = op.mode;
    const float* X = op.A;
    auto getcw = [&](int e, int& c, float& w) {
      int off = e - e_lo;
      if (off < IDXCAP) { c = idxbuf[off]; w = wbuf[off]; }
      else { c = op.gcol[e]; w = op.wsrc ? op.wsrc[c] : 0.f; }
    };
#pragma unroll
    for (int i = 0; i < 4; ++i) {
      int f4 = t + i * 256;
      int row = f4 >> 5, ln = f4 & 31;
      int r = row0 + row;
      float4 s = make_float4(0.f, 0.f, 0.f, 0.f);
      int e0 = 0, e1 = 0;
      float rs = 0.f;
      if (r < N) {
        e0 = op.grp[r]; e1 = op.grp[r + 1];
        if (mode >= 2) rs = op.rowsc[r];
      }
      float z = 0.f;
      if (mode == 2 && r < N) {
        float4 xs_ = *(const float4*)(X + (size_t)r * 128 + ln * 4);
        float rr = rs * rs;
        s.x = rr * xs_.x; s.y = rr * xs_.y; s.z = rr * xs_.z; s.w = rr * xs_.w;
      }
      int e = e0;
      for (; e + 1 < e1; e += 2) {
        int c0, c1; float w0, w1;
        getcw(e, c0, w0);
        getcw(e + 1, c1, w1);
        float p0, p1;
        if (mode == 3) {
          float v0 = w0 + rs; v0 = v0 > 0.f ? v0 : 0.2f * v0;
          float v1 = w1 + rs; v1 = v1 > 0.f ? v1 : 0.2f * v1;
          p0 = __expf(v0); p1 = __expf(v1); z += p0 + p1;
        } else if (mode == 2) { p0 = w0 * rs; p1 = w1 * rs; }
        else { p0 = 1.f; p1 = 1.f; }
        float4 a = *(const float4*)(X + (size_t)c0 * 128 + ln * 4);
        float4 b = *(const float4*)(X + (size_t)c1 * 128 + ln * 4);
        s.x += p0 * a.x + p1 * b.x; s.y += p0 * a.y + p1 * b.y;
        s.z += p0 * a.z + p1 * b.z; s.w += p0 * a.w + p1 * b.w;
      }
      if (e < e1) {
        int c; float w;
        getcw(e, c, w);
        float p;
        if (mode == 3) {
          float v = w + rs; v = v > 0.f ? v : 0.2f * v;
          p = __expf(v); z += p;
        } else if (mode == 2) p = w * rs;
        else p = 1.f;
        float4 a = *(const float4*)(X + (size_t)c * 128 + ln * 4);
        s.x += p * a.x; s.y += p * a.y; s.z += p * a.z; s.w += p * a.w;
      }
      if (mode == 1) {
        float inv = 1.f / fmaxf((float)(e1 - e0), 1.f);
        s.x *= inv; s.y *= inv; s.z *= inv; s.w *= inv;
      } else if (mode == 3) {
        float inv = (e1 > e0) ? 1.f / z : 0.f;
        s.x *= inv; s.y *= inv; s.z *= inv; s.w *= inv;
      }
      storeAhl(row, ln, s);
    }
  };

  auto accum = [&](const short* __restrict__ WH, const short* __restrict__ WL) {
#pragma unroll
    for (int kg = 0; kg < 4; ++kg) {
      short8v bhi[2], blo[2];
#pragma unroll
      for (int ct = 0; ct < 2; ++ct) {
        size_t o = (size_t)(colbase + ct * 16 + cn) * 128 + kg * 32 + g * 8;
        bhi[ct] = *(const short8v*)(WH + o);
        blo[ct] = *(const short8v*)(WL + o);
      }
#pragma unroll
      for (int rt = 0; rt < 2; ++rt) {
        const int ao = (rt * 16 + cn) * 136 + kg * 32 + g * 8;
        const short8v ah = *(const short8v*)(Ah + ao);
        const short8v al = *(const short8v*)(Al + ao);
#pragma unroll
        for (int ct = 0; ct < 2; ++ct) {
          acc[rt][ct] = __builtin_amdgcn_mfma_f32_16x16x32_bf16(ah, bhi[ct], acc[rt][ct], 0, 0, 0);
          acc[rt][ct] = __builtin_amdgcn_mfma_f32_16x16x32_bf16(al, bhi[ct], acc[rt][ct], 0, 0, 0);
          acc[rt][ct] = __builtin_amdgcn_mfma_f32_16x16x32_bf16(ah, blo[ct], acc[rt][ct], 0, 0, 0);
        }
      }
    }
  };

  // ---- operand 0 ----
  if (o0.mode) {
    prefetch(o0);
    __syncthreads();
    stage_gather(o0);
  } else {
    stageA(o0.A);
  }
  __syncthreads();
  if (hasO1 && o1.mode) prefetch(o1);   // overlap idx prefetch with accum0
  accum(o0.WH, o0.WL);
  // ---- operand 1 ----
  if (hasO1) {
    __syncthreads();
    if (o1.mode) stage_gather(o1); else stageA(o1.A);
    __syncthreads();
    accum(o1.WH, o1.WL);
  }
  __syncthreads();

  // acc -> LDS C-tile (C/D layout col=lane&15, row=(lane>>4)*4+reg)
#pragma unroll
  for (int rt = 0; rt < 2; ++rt)
#pragma unroll
    for (int ct = 0; ct < 2; ++ct)
#pragma unroll
      for (int r = 0; r < 4; ++r)
        Cf[(rt * 16 + g * 4 + r) * CF_LD + colbase + ct * 16 + cn] = acc[rt][ct][r];
  __syncthreads();

  float4* C4 = (float4*)(C + (size_t)row0 * 128);
#pragma unroll
  for (int i = 0; i < 4; ++i) {
    int f4 = t + i * 256;
    int row = f4 >> 5, c4 = f4 & 31;
    if (row0 + row < N) {
      float4 v = *(const float4*)(Cf + row * CF_LD + c4 * 4);
      if (bias) {
        float4 bv = *(const float4*)(bias + c4 * 4);
        v.x += bv.x; v.y += bv.y; v.z += bv.z; v.w += bv.w;
      }
      if (bias2) {
        float4 bv = *(const float4*)(bias2 + c4 * 4);
        v.x += bv.x; v.y += bv.y; v.z += bv.z; v.w += bv.w;
      }
      if (addin) {
        float4 av = *(const float4*)(addin + (size_t)(row0 + row) * 128 + c4 * 4);
        v.x += av.x; v.y += av.y; v.z += av.z; v.w += av.w;
      }
      if (relu) {
        v.x = fmaxf(v.x, 0.f); v.y = fmaxf(v.y, 0.f);
        v.z = fmaxf(v.z, 0.f); v.w = fmaxf(v.w, 0.f);
      }
      C4[f4] = v;
      if (avec) {
        float4 av = *(const float4*)(avec + c4 * 4);
        float p = v.x * av.x + v.y * av.y + v.z * av.z + v.w * av.w;
#pragma unroll
        for (int o = 1; o < 32; o <<= 1) p += __shfl_xor(p, o);
        if (c4 == 0) adot[row0 + row] = p;
      }
      if (avec2) {
        float4 av = *(const float4*)(avec2 + c4 * 4);
        float p = v.x * av.x + v.y * av.y + v.z * av.z + v.w * av.w;
#pragma unroll
        for (int o = 1; o < 32; o <<= 1) p += __shfl_xor(p, o);
        if (c4 == 0) adot2[row0 + row] = p;
      }
    }
  }
}

// ======================= row dots (one wave / node) =======================
__global__ void k_rowdot(const float* __restrict__ x, const float* __restrict__ a,
                         float* __restrict__ out, int N)
{
  int wid = blockIdx.x * 4 + (threadIdx.x >> 6);
  int lane = threadIdx.x & 63;
  if (wid >= N) return;
  float2 xv = ((const float2*)x)[(size_t)wid * 64 + lane];
  float2 av = ((const float2*)a)[lane];
  float v = fmaf(xv.y, av.y, xv.x * av.x);
#pragma unroll
  for (int o = 32; o > 0; o >>= 1) v += __shfl_down(v, o);
  if (lane == 0) out[wid] = v;
}

__global__ void k_rowdot2(const float* __restrict__ x, const float* __restrict__ a1,
                          const float* __restrict__ a2, float* __restrict__ o1,
                          float* __restrict__ o2, int N)
{
  int wid = blockIdx.x * 4 + (threadIdx.x >> 6);
  int lane = threadIdx.x & 63;
  if (wid >= N) return;
  float2 xv = ((const float2*)x)[(size_t)wid * 64 + lane];
  float2 av1 = ((const float2*)a1)[lane];
  float2 av2 = ((const float2*)a2)[lane];
  float v1 = fmaf(xv.y, av1.y, xv.x * av1.x);
  float v2 = fmaf(xv.y, av2.y, xv.x * av2.x);
#pragma unroll
  for (int o = 32; o > 0; o >>= 1) { v1 += __shfl_down(v1, o); v2 += __shfl_down(v2, o); }
  if (lane == 0) { o1[wid] = v1; o2[wid] = v2; }
}

// ================= batched matvec =================
struct MTab { const float* W[8]; const float* a[8]; };
__global__ __launch_bounds__(128) void k_matvec8(MTab tb, float* __restrict__ wv)
{
  __shared__ float as[128];
  int m = blockIdx.x, i = threadIdx.x;
  as[i] = tb.a[m][i];
  __syncthreads();
  const float* W = tb.W[m];
  float v = 0.f;
  for (int j = 0; j < 128; ++j) v = fmaf(W[i * 128 + j], as[j], v);
  wv[m * 128 + i] = v;
}

// ======================= batched CSR build =======================
struct HTab { const int* key[6]; int* cnt[6]; unsigned short* rank[6]; int bo[7]; int n[6]; };
__global__ void k_hist_rank_all(HTab tb) {
  int bi = blockIdx.x, ty = 0;
  while (ty < 5 && bi >= tb.bo[ty + 1]) ++ty;
  int i = (bi - tb.bo[ty]) * 256 + threadIdx.x;
  if (i < tb.n[ty])
    tb.rank[ty][i] = (unsigned short)atomicAdd(&tb.cnt[ty][tb.key[ty][i]], 1);
}

struct FTab { const int* es[6]; const int* ed[6]; const int* rp[6];
              const unsigned short* rank[6]; int* col[6]; int bo[7]; int n[6]; };
__global__ void k_fill_all(FTab tb) {
  int bi = blockIdx.x, ty = 0;
  while (ty < 5 && bi >= tb.bo[ty + 1]) ++ty;
  int e = (bi - tb.bo[ty]) * 256 + threadIdx.x;
  if (e >= tb.n[ty]) return;
  int p = tb.rp[ty][tb.ed[ty][e]] + (int)tb.rank[ty][e];
  tb.col[ty][p] = tb.es[ty][e];
}

struct STab { int* rp[6]; int* bs[6]; int n[6]; int bo[7]; };

__global__ __launch_bounds__(256) void k_scan_partial_all(STab tb) {
  __shared__ int red[256];
  int bi = blockIdx.x, ty = 0;
  while (ty < 5 && bi >= tb.bo[ty + 1]) ++ty;
  int lb = bi - tb.bo[ty];
  const int* rp = tb.rp[ty];
  const int N = tb.n[ty];
  const int t = threadIdx.x, base = lb * 4096;
  int s = 0;
  for (int i = t; i < 4096; i += 256) {
    int idx = base + i;
    if (idx < N) s += rp[idx];
  }
  red[t] = s;
  __syncthreads();
  for (int ofs = 128; ofs > 0; ofs >>= 1) {
    if (t < ofs) red[t] += red[t + ofs];
    __syncthreads();
  }
  if (t == 0) tb.bs[ty][lb] = red[0];
}

__global__ __launch_bounds__(256) void k_scan_bsums_all(STab tb) {
  __shared__ int sh[256];
  const int ty = blockIdx.x;
  const int nb = (tb.n[ty] + 4095) / 4096;
  const int t = threadIdx.x;
  int v = (t < nb) ? tb.bs[ty][t] : 0;
  sh[t] = v;
  __syncthreads();
  for (int ofs = 1; ofs < 256; ofs <<= 1) {
    int u = (t >= ofs) ? sh[t - ofs] : 0;
    __syncthreads();
    sh[t] += u;
    __syncthreads();
  }
  if (t < nb) tb.bs[ty][t] = sh[t] - v;
  if (t == 255) tb.rp[ty][tb.n[ty]] = sh[255];
}

__global__ __launch_bounds__(256) void k_scan_final_all(STab tb) {
  __shared__ int sh[4096 + 256];
  __shared__ int tsum[256];
  int bi = blockIdx.x, ty = 0;
  while (ty < 5 && bi >= tb.bo[ty + 1]) ++ty;
  int lb = bi - tb.bo[ty];
  int* rp = tb.rp[ty];
  const int N = tb.n[ty];
  const int t = threadIdx.x, base = lb * 4096;
  auto mp = [](int i) { return i + (i >> 4); };
#pragma unroll
  for (int i = 0; i < 16; ++i) {
    int idx = base + i * 256 + t;
    sh[mp(i * 256 + t)] = (idx < N) ? rp[idx] : 0;
  }
  __syncthreads();
  int s = 0;
#pragma unroll
  for (int j = 0; j < 16; ++j) s += sh[mp(t * 16 + j)];
  tsum[t] = s;
  __syncthreads();
  for (int ofs = 1; ofs < 256; ofs <<= 1) {
    int u = (t >= ofs) ? tsum[t - ofs] : 0;
    __syncthreads();
    tsum[t] += u;
    __syncthreads();
  }
  int pre = tsum[t] - s + tb.bs[ty][lb];
#pragma unroll
  for (int j = 0; j < 16; ++j) {
    int v = sh[mp(t * 16 + j)];
    sh[mp(t * 16 + j)] = pre;
    pre += v;
  }
  __syncthreads();
#pragma unroll
  for (int i = 0; i < 16; ++i) {
    int idx = base + i * 256 + t;
    if (idx < N) rp[idx] = sh[mp(i * 256 + t)];
  }
}

struct BTab { const int* b[5]; int n[5]; };
__global__ __launch_bounds__(512) void k_runptr(BTab tb, int* __restrict__ rpb_all) {
  const int ty = blockIdx.x;
  const int* b = tb.b[ty];
  const int N = tb.n[ty];
  const int t = threadIdx.x;
  int lo = 0, hi = N;
  while (lo < hi) {
    int mid = (lo + hi) >> 1;
    if (b[mid] < t) lo = mid + 1; else hi = mid;
  }
  rpb_all[ty * RPB + t] = lo;
  if (t == 0) rpb_all[ty * RPB + GNUM] = N;
}

struct DTab { const int* rp[2]; float* dis[2]; int n[2]; int bo[3]; };
__global__ void k_dis2(DTab tb) {
  int bi = blockIdx.x, ty = (bi >= tb.bo[1]) ? 1 : 0;
  int n = (bi - tb.bo[ty]) * 256 + threadIdx.x;
  if (n < tb.n[ty]) tb.dis[ty][n] = rsqrtf((float)(tb.rp[ty][n + 1] - tb.rp[ty][n]) + 1.f);
}

// ============ segment pooling ============
__global__ __launch_bounds__(256) void k_pool_seg(
    const float* __restrict__ x, const int* __restrict__ rpb,
    float* __restrict__ pool, int col_off)
{
  __shared__ float2 red2[4][64];
  const int g = blockIdx.x;
  const int t = threadIdx.x, w = t >> 6, lane = t & 63;
  const int n0 = rpb[g], n1 = rpb[g + 1];
  const float2* x2 = (const float2*)x;
  float a0 = 0.f, a1 = 0.f, b0 = 0.f, b1 = 0.f;
  int n = n0 + w;
  for (; n + 4 < n1; n += 8) {
    float2 vA = x2[(size_t)n * 64 + lane];
    float2 vB = x2[(size_t)(n + 4) * 64 + lane];
    a0 += vA.x; a1 += vA.y; b0 += vB.x; b1 += vB.y;
  }
  if (n < n1) { float2 vA = x2[(size_t)n * 64 + lane]; a0 += vA.x; a1 += vA.y; }
  red2[w][lane] = make_float2(a0 + b0, a1 + b1);
  __syncthreads();
  if (t < 64) {
    float2 r0 = red2[0][t], r1 = red2[1][t], r2 = red2[2][t], r3 = red2[3][t];
    float inv = 1.f / fmaxf((float)(n1 - n0), 1.f);
    ((float2*)(pool + (size_t)g * 640 + col_off))[t] =
        make_float2((r0.x + r1.x + r2.x + r3.x) * inv,
                    (r0.y + r1.y + r2.y + r3.y) * inv);
  }
}

// ======================= final MLP =======================
__global__ void k_mlp(const float* __restrict__ pool,
                      const float* __restrict__ W1, const float* __restrict__ b1,
                      const float* __restrict__ W2, const float* __restrict__ b2,
                      float* __restrict__ out)
{
  __shared__ float emb[640];
  __shared__ float red[128];
  const int g = blockIdx.x, t = threadIdx.x;
  for (int i = t; i < 640; i += 128) emb[i] = pool[(size_t)g * 640 + i];
  __syncthreads();
  float acc = b1[t];
  for (int i = 0; i < 640; ++i) acc = fmaf(emb[i], W1[i * 128 + t], acc);
  float h = fmaxf(acc, 0.f);
  red[t] = h * W2[t];
  __syncthreads();
  for (int s = 64; s > 0; s >>= 1) {
    if (t < s) red[t] += red[t + s];
    __syncthreads();
  }
  if (t == 0) out[g] = red[0] + b2[0];
}

// ======================= host =======================
extern "C" void kernel_launch(void* const* d_in, const int* in_sizes, int n_in,
                              void* d_out, int out_size, void* d_ws, size_t ws_size,
                              hipStream_t stream)
{
  auto fin = [&](int i) { return (const float*)d_in[i]; };
  auto iin = [&](int i) { return (const int*)d_in[i]; };

  const float *x_cd = fin(0), *x_seq = fin(1), *x_anno = fin(2), *x_range = fin(3), *x_md = fin(4);
  const int *ei_seq = iin(5), *ei_anno = iin(6), *ei_range = iin(7),
            *ei_comp = iin(8), *ei_cc = iin(9), *ei_mm = iin(10);
  const int *b_cd = iin(11), *b_seq = iin(12), *b_anno = iin(13), *b_range = iin(14), *b_md = iin(15);

  const int N_CD = in_sizes[0] / HD, N_SEQ = in_sizes[1] / HD, N_ANNO = in_sizes[2] / HD,
            N_RANGE = in_sizes[3] / HD, N_MD = in_sizes[4] / HD;
  const int E_seq = in_sizes[5] / 2, E_anno = in_sizes[6] / 2, E_range = in_sizes[7] / 2,
            E_comp = in_sizes[8] / 2, E_cc = in_sizes[9] / 2, E_mm = in_sizes[10] / 2;
  const int N_OTH = max(max(N_SEQ, N_ANNO), N_RANGE);

  auto WLm = [&](int i, int l) { return fin(i) + (size_t)l * HD * HD; };
  auto WLv = [&](int i, int l) { return fin(i) + (size_t)l * HD; };

  // ---- workspace layout ----
  float* ws = (float*)d_ws;
  size_t off = 0;
  auto alloc = [&](size_t n) { float* p = ws + off; off += (n + 3) & ~(size_t)3; return p; };
  float* xcd1 = alloc((size_t)N_CD * HD);
  float* xmd1 = alloc((size_t)N_MD * HD);
  float* xoth = alloc((size_t)N_OTH * HD);
  float* acc  = alloc((size_t)N_CD * HD);
  float* t1   = alloc((size_t)N_CD * HD);
  float* sA = alloc((size_t)N_CD);
  float* sB = alloc((size_t)N_CD);
  float* sC = alloc((size_t)N_CD);
  float* sD = alloc((size_t)N_CD);
  float* sE = alloc((size_t)N_CD);
  float* sF = alloc((size_t)N_CD);
  float* dis_cc = alloc((size_t)N_CD);
  float* dis_mm = alloc((size_t)N_MD);
  float* wv8 = alloc(8 * HD);
  float* pool = alloc((size_t)GNUM * 5 * HD);
  short* whi = (short*)(ws + off); off += (size_t)16 * 16384 / 2;
  short* wlo = (short*)(ws + off); off += (size_t)16 * 16384 / 2;
  auto alloci = [&](size_t n) { int* p = (int*)(ws + off); off += (n + 3) & ~(size_t)3; return p; };
  int* bsall = alloci(6 * 256);
  int* rpb_all = alloci(5 * RPB);
  int Nds[6] = {N_SEQ, N_ANNO, N_RANGE, N_CD, N_CD, N_MD};
  int Es[6]  = {E_seq, E_anno, E_range, E_comp, E_cc, E_mm};
  int* rps[6];
  int* rp0 = alloci(0);
  { size_t tot = 0; for (int i = 0; i < 6; ++i) tot += (size_t)Nds[i] + 1;
    int* p = alloci(tot); rp0 = p;
    for (int i = 0; i < 6; ++i) { rps[i] = p; p += Nds[i] + 1; } }
  size_t rp_tot_bytes = 0; for (int i = 0; i < 6; ++i) rp_tot_bytes += ((size_t)Nds[i] + 1) * 4;
  unsigned short* ranks[6];
  for (int i = 0; i < 6; ++i) ranks[i] = (unsigned short*)alloci(((size_t)Es[i] + 1) / 2);
  int* cols[6];  for (int i = 0; i < 6; ++i) cols[i] = alloci((size_t)Es[i]);
  (void)n_in;

  if (off * sizeof(float) > ws_size) {
    hipMemsetAsync(d_out, 0, (size_t)out_size * sizeof(float), stream);
    return;
  }

  auto ew = [&](size_t elems) { return dim3((unsigned)((elems + 255) / 256)); };
  auto nw = [&](int N) { return dim3((unsigned)((N + 3) / 4)); };

  // ---- pre-split all GEMM weights (slots: 0:16 1:18 2:19 3:21 4:22 5:27 6:32 7:34)
  WTab tab;
  tab.p[0] = fin(16); tab.p[1] = fin(18); tab.p[2] = fin(19); tab.p[3] = fin(21);
  tab.p[4] = fin(22); tab.p[5] = fin(27); tab.p[6] = fin(32); tab.p[7] = fin(34);
  k_split_w<<<dim3(1024), dim3(256), 0, stream>>>(tab, whi, wlo);

  // ---- 8 GAT matvecs: s/d for comp L0,L1 and range L0,L1 ----
  MTab mt;
  mt.W[0] = WLm(22, 0); mt.a[0] = WLv(24, 0);
  mt.W[1] = WLm(23, 0); mt.a[1] = WLv(25, 0);
  mt.W[2] = WLm(22, 1); mt.a[2] = WLv(24, 1);
  mt.W[3] = WLm(23, 1); mt.a[3] = WLv(25, 1);
  mt.W[4] = WLm(27, 0); mt.a[4] = WLv(29, 0);
  mt.W[5] = WLm(28, 0); mt.a[5] = WLv(30, 0);
  mt.W[6] = WLm(27, 1); mt.a[6] = WLv(29, 1);
  mt.W[7] = WLm(28, 1); mt.a[7] = WLv(30, 1);
  k_matvec8<<<dim3(8), dim3(128), 0, stream>>>(mt, wv8);

  // ---- input-side attention scalars ----
  k_rowdot<<<nw(N_MD), dim3(256), 0, stream>>>(x_md, wv8 + 0 * 128, sA, N_MD);
  k_rowdot2<<<nw(N_CD), dim3(256), 0, stream>>>(x_cd, wv8 + 1 * 128, wv8 + 4 * 128,
                                                sB, sC, N_CD);
  k_rowdot<<<nw(N_RANGE), dim3(256), 0, stream>>>(x_range, wv8 + 5 * 128, sD, N_RANGE);

  // ---- run-pointers for sorted batch vectors ----
  {
    BTab bt;
    bt.b[0] = b_cd; bt.n[0] = N_CD;  bt.b[1] = b_seq; bt.n[1] = N_SEQ;
    bt.b[2] = b_anno; bt.n[2] = N_ANNO;  bt.b[3] = b_range; bt.n[3] = N_RANGE;
    bt.b[4] = b_md; bt.n[4] = N_MD;
    k_runptr<<<dim3(5), dim3(512), 0, stream>>>(bt, rpb_all);
  }

  // ---- batched CSR build ----
  const int* ess[6] = {ei_seq, ei_anno, ei_range, ei_comp, ei_cc, ei_mm};
  const int* eds[6] = {ei_seq + E_seq, ei_anno + E_anno, ei_range + E_range,
                       ei_comp + E_comp, ei_cc + E_cc, ei_mm + E_mm};
  hipMemsetAsync(rp0, 0, rp_tot_bytes, stream);
  {
    HTab ht; int b = 0;
    for (int i = 0; i < 6; ++i) {
      ht.key[i] = eds[i]; ht.cnt[i] = rps[i]; ht.rank[i] = ranks[i];
      ht.bo[i] = b; b += (Es[i] + 255) / 256; ht.n[i] = Es[i];
    }
    ht.bo[6] = b;
    k_hist_rank_all<<<dim3(b), dim3(256), 0, stream>>>(ht);
  }
  {
    STab st; int b = 0;
    for (int i = 0; i < 6; ++i) {
      st.rp[i] = rps[i]; st.bs[i] = bsall + i * 256;
      st.n[i] = Nds[i]; st.bo[i] = b; b += (Nds[i] + 4095) / 4096;
    }
    st.bo[6] = b;
    k_scan_partial_all<<<dim3(b), dim3(256), 0, stream>>>(st);
    k_scan_bsums_all<<<dim3(6), dim3(256), 0, stream>>>(st);
    k_scan_final_all<<<dim3(b), dim3(256), 0, stream>>>(st);
  }
  {
    FTab ft; int b = 0;
    for (int i = 0; i < 6; ++i) {
      ft.es[i] = ess[i]; ft.ed[i] = eds[i]; ft.rp[i] = rps[i]; ft.rank[i] = ranks[i];
      ft.col[i] = cols[i]; ft.bo[i] = b; b += (Es[i] + 255) / 256; ft.n[i] = Es[i];
    }
    ft.bo[6] = b;
    k_fill_all<<<dim3(b), dim3(256), 0, stream>>>(ft);
  }
  int *rp_seq = rps[0], *rp_anno = rps[1], *rp_range = rps[2],
      *rp_comp = rps[3], *rp_cc = rps[4], *rp_mm = rps[5];
  int *col_seq = cols[0], *col_anno = cols[1], *col_range = cols[2],
      *col_comp = cols[3], *col_cc = cols[4], *col_mm = cols[5];
  {
    DTab dt;
    dt.rp[0] = rp_cc; dt.dis[0] = dis_cc; dt.n[0] = N_CD;
    dt.rp[1] = rp_mm; dt.dis[1] = dis_mm; dt.n[1] = N_MD;
    dt.bo[0] = 0; dt.bo[1] = (N_CD + 255) / 256;
    dt.bo[2] = dt.bo[1] + (N_MD + 255) / 256;
    k_dis2<<<dim3(dt.bo[2]), dim3(256), 0, stream>>>(dt);
  }

  auto WHp = [&](int sidx, int layer) { return whi + (size_t)(sidx * 2 + layer) * 16384; };
  auto WLp = [&](int sidx, int layer) { return wlo + (size_t)(sidx * 2 + layer) * 16384; };

  auto mkop = [&](int mode, const float* A, int sidx, int layer,
                  const int* grp, const int* gcol,
                  const float* wsrc, const float* rowsc) {
    COp o;
    o.A = A; o.WH = WHp(sidx, layer); o.WL = WLp(sidx, layer);
    o.grp = grp; o.gcol = gcol; o.wsrc = wsrc; o.rowsc = rowsc; o.mode = mode;
    return o;
  };
  auto launch = [&](COp o0, COp o1, int hasO1, float* C, const float* bias,
                    const float* bias2, const float* addin, int N, int relu,
                    const float* avec, float* adot, const float* avec2, float* adot2) {
    k_gemm_conv<<<dim3((N + TM - 1) / TM), dim3(256), 0, stream>>>(
        o0, o1, hasO1, C, bias, bias2, addin, N, relu, avec, adot, avec2, adot2);
  };
  auto do_pool = [&](const float* x, int type) {
    k_pool_seg<<<dim3(GNUM), dim3(256), 0, stream>>>(x, rpb_all + type * RPB, pool, type * HD);
  };
  COp nop = {};

  // ---------- L0 fused CD: GAT(x_md,comp) + GCN(x_cd,cc) -> xcd1 ----------
  launch(mkop(3, x_md, 4, 0, rp_comp, col_comp, sA, sB),
         mkop(2, x_cd, 6, 0, rp_cc, col_cc, dis_cc, dis_cc), 1,
         xcd1, WLv(26, 0), WLv(33, 0), nullptr, N_CD, 1,
         wv8 + 3 * 128, sB, wv8 + 6 * 128, sE);
  // ---------- L0 mm GCN -> xmd1 (dot: comp1 sAs -> sA) ----------
  launch(mkop(2, x_md, 7, 0, rp_mm, col_mm, dis_mm, dis_mm), nop, 0,
         xmd1, WLv(35, 0), nullptr, nullptr, N_MD, 1,
         wv8 + 2 * 128, sA, nullptr, nullptr);
  // ---------- L1 fused CD: GAT(xmd1,comp) + GCN(xcd1,cc) -> acc ----------
  launch(mkop(3, xmd1, 4, 1, rp_comp, col_comp, sA, sB),
         mkop(2, xcd1, 6, 1, rp_cc, col_cc, dis_cc, dis_cc), 1,
         acc, WLv(26, 1), WLv(33, 1), nullptr, N_CD, 1,
         nullptr, nullptr, nullptr, nullptr);
  do_pool(acc, 0);
  // ---------- L1 mm GCN -> acc ----------
  launch(mkop(2, xmd1, 7, 1, rp_mm, col_mm, dis_mm, dis_mm), nop, 0,
         acc, WLv(35, 1), nullptr, nullptr, N_MD, 1,
         nullptr, nullptr, nullptr, nullptr);
  do_pool(acc, 4);

  // ---------- SEQ (SAGE: mean gather + dense self) ----------
  launch(mkop(1, x_cd, 0, 0, rp_seq, col_seq, nullptr, nullptr),
         mkop(0, x_seq, 1, 0, nullptr, nullptr, nullptr, nullptr), 1,
         xoth, WLv(17, 0), nullptr, nullptr, N_SEQ, 1, nullptr, nullptr, nullptr, nullptr);
  launch(mkop(1, xcd1, 0, 1, rp_seq, col_seq, nullptr, nullptr),
         mkop(0, xoth, 1, 1, nullptr, nullptr, nullptr, nullptr), 1,
         acc, WLv(17, 1), nullptr, nullptr, N_SEQ, 1, nullptr, nullptr, nullptr, nullptr);
  do_pool(acc, 1);
  // ---------- ANNO ----------
  launch(mkop(1, x_cd, 2, 0, rp_anno, col_anno, nullptr, nullptr),
         mkop(0, x_anno, 3, 0, nullptr, nullptr, nullptr, nullptr), 1,
         t1, WLv(20, 0), nullptr, nullptr, N_ANNO, 1, nullptr, nullptr, nullptr, nullptr);
  launch(mkop(1, xcd1, 2, 1, rp_anno, col_anno, nullptr, nullptr),
         mkop(0, t1, 3, 1, nullptr, nullptr, nullptr, nullptr), 1,
         acc, WLv(20, 1), nullptr, nullptr, N_ANNO, 1, nullptr, nullptr, nullptr, nullptr);
  do_pool(acc, 2);
  // ---------- RANGE (GAT) ----------
  launch(mkop(3, x_cd, 5, 0, rp_range, col_range, sC, sD), nop, 0,
         xoth, WLv(31, 0), nullptr, nullptr, N_RANGE, 1,
         wv8 + 7 * 128, sF, nullptr, nullptr);
  launch(mkop(3, xcd1, 5, 1, rp_range, col_range, sE, sF), nop, 0,
         acc, WLv(31, 1), nullptr, nullptr, N_RANGE, 1,
         nullptr, nullptr, nullptr, nullptr);
  do_pool(acc, 3);

  k_mlp<<<dim3(GNUM), dim3(128), 0, stream>>>(
      pool, fin(36), fin(37), fin(38), fin(39), (float*)d_out);
}

// Round 23
// 844.708 us; speedup vs baseline: 1.1697x; 1.0470x over previous
//
#include <hip/hip_runtime.h>

#define HD 128
#define GNUM 512
#define RPB 520
#define IDXCAP 512
#define TM 32

typedef __attribute__((ext_vector_type(8))) short short8v;
typedef __attribute__((ext_vector_type(4))) float f32x4;

// RNE split: a ~= hi + lo (both bf16)
__device__ __forceinline__ void split1(float a, short& h, short& l) {
  unsigned u = __float_as_uint(a);
  unsigned hb = (u + 0x7FFFu + ((u >> 16) & 1u)) & 0xFFFF0000u;
  h = (short)(hb >> 16);
  float rest = a - __uint_as_float(hb);
  unsigned u2 = __float_as_uint(rest);
  l = (short)((u2 + 0x7FFFu + ((u2 >> 16) & 1u)) >> 16);
}

// ============ W pre-split: fp32 [k][n] -> bf16 hi/lo TRANSPOSED [n][k] ============
struct WTab { const float* p[8]; };
__global__ __launch_bounds__(256) void k_split_w(WTab tab, short* __restrict__ whi,
                                                 short* __restrict__ wlo)
{
  int m = blockIdx.x >> 6;
  int i = (blockIdx.x & 63) * 256 + threadIdx.x;
  const float* W = tab.p[m >> 1] + (m & 1) * 16384;
  int k = i >> 7, n = i & 127;
  short h, l;
  split1(W[k * 128 + n], h, l);
  whi[m * 16384 + n * 128 + k] = h;
  wlo[m * 16384 + n * 128 + k] = l;
}

// ============ unified conv GEMM: C = AGG0(A0)@W0 (+ AGG1(A1)@W1) (+biases,relu) ===
// per-op mode: 0 dense, 1 SAGE mean, 2 GCN (w=wsrc[c]*rowsc[r] + self rowsc^2),
// 3 GAT softmax (w=exp(lrelu(wsrc[c]+rowsc[r]))/z).
// Optional fused FINAL-OUTPUT row-dots, and fused segment-POOL accumulation
// (bvec sorted graph ids; atomicAdd sums into poolbuf; C may be nullptr).
struct COp {
  const float* A; const short* WH; const short* WL;
  const int* grp; const int* gcol;
  const float* wsrc; const float* rowsc; int mode;
};
#define CF_LD 132
__global__ __launch_bounds__(256) void k_gemm_conv(
    COp o0, COp o1, int hasO1,
    float* __restrict__ C, const float* __restrict__ bias, const float* __restrict__ bias2,
    const float* addin, int N, int relu,
    const float* __restrict__ avec, float* __restrict__ adot,
    const float* __restrict__ avec2, float* __restrict__ adot2,
    const int* __restrict__ bvec, float* __restrict__ poolbuf, int coloff)
{
  __shared__ char smem[TM * 136 * 2 * 2];        // 17408 B
  __shared__ int idxbuf[IDXCAP];
  __shared__ float wbuf[IDXCAP];
  __shared__ int bsh[TM];
  short* Ah = (short*)smem;
  short* Al = Ah + TM * 136;
  float* Cf = (float*)smem;

  const int t = threadIdx.x;
  const int row0 = blockIdx.x * TM;
  const int lane = t & 63, wid = t >> 6;
  const int g = lane >> 4, cn = lane & 15;
  const int colbase = wid * 32;

  f32x4 zero = {0.f, 0.f, 0.f, 0.f};
  f32x4 acc[2][2];
#pragma unroll
  for (int rt = 0; rt < 2; ++rt) { acc[rt][0] = zero; acc[rt][1] = zero; }

  auto storeAhl = [&](int row, int ln, float4 s) {
    short4 h, l;
    split1(s.x, h.x, l.x); split1(s.y, h.y, l.y);
    split1(s.z, h.z, l.z); split1(s.w, h.w, l.w);
    *(short4*)(Ah + row * 136 + ln * 4) = h;
    *(short4*)(Al + row * 136 + ln * 4) = l;
  };

  auto stageA = [&](const float* __restrict__ A) {
#pragma unroll
    for (int i = 0; i < 4; ++i) {
      int f4 = t + i * 256;
      int row = f4 >> 5, c4 = f4 & 31;
      float4 v = make_float4(0.f, 0.f, 0.f, 0.f);
      if (row0 + row < N) v = ((const float4*)(A + (size_t)row0 * 128))[f4];
      storeAhl(row, c4, v);
    }
  };

  auto prefetch = [&](const COp& op) {
    const int row_end = min(row0 + TM, N);
    const int e_lo = op.grp[row0];
    const int cnt = min(op.grp[row_end] - e_lo, IDXCAP);
    for (int k = t; k < cnt; k += 256) {
      int idx = op.gcol[e_lo + k];
      idxbuf[k] = idx;
      if (op.wsrc) wbuf[k] = op.wsrc[idx];
    }
  };

  auto stage_gather = [&](const COp& op) {
    const int e_lo = op.grp[row0];
    const int mode = op.mode;
    const float* X = op.A;
    auto getcw = [&](int e, int& c, float& w) {
      int off = e - e_lo;
      if (off < IDXCAP) { c = idxbuf[off]; w = wbuf[off]; }
      else { c = op.gcol[e]; w = op.wsrc ? op.wsrc[c] : 0.f; }
    };
#pragma unroll
    for (int i = 0; i < 4; ++i) {
      int f4 = t + i * 256;
      int row = f4 >> 5, ln = f4 & 31;
      int r = row0 + row;
      float4 s = make_float4(0.f, 0.f, 0.f, 0.f);
      int e0 = 0, e1 = 0;
      float rs = 0.f;
      if (r < N) {
        e0 = op.grp[r]; e1 = op.grp[r + 1];
        if (mode >= 2) rs = op.rowsc[r];
      }
      float z = 0.f;
      if (mode == 2 && r < N) {
        float4 xs_ = *(const float4*)(X + (size_t)r * 128 + ln * 4);
        float rr = rs * rs;
        s.x = rr * xs_.x; s.y = rr * xs_.y; s.z = rr * xs_.z; s.w = rr * xs_.w;
      }
      int e = e0;
      for (; e + 1 < e1; e += 2) {
        int c0, c1; float w0, w1;
        getcw(e, c0, w0);
        getcw(e + 1, c1, w1);
        float p0, p1;
        if (mode == 3) {
          float v0 = w0 + rs; v0 = v0 > 0.f ? v0 : 0.2f * v0;
          float v1 = w1 + rs; v1 = v1 > 0.f ? v1 : 0.2f * v1;
          p0 = __expf(v0); p1 = __expf(v1); z += p0 + p1;
        } else if (mode == 2) { p0 = w0 * rs; p1 = w1 * rs; }
        else { p0 = 1.f; p1 = 1.f; }
        float4 a = *(const float4*)(X + (size_t)c0 * 128 + ln * 4);
        float4 b = *(const float4*)(X + (size_t)c1 * 128 + ln * 4);
        s.x += p0 * a.x + p1 * b.x; s.y += p0 * a.y + p1 * b.y;
        s.z += p0 * a.z + p1 * b.z; s.w += p0 * a.w + p1 * b.w;
      }
      if (e < e1) {
        int c; float w;
        getcw(e, c, w);
        float p;
        if (mode == 3) {
          float v = w + rs; v = v > 0.f ? v : 0.2f * v;
          p = __expf(v); z += p;
        } else if (mode == 2) p = w * rs;
        else p = 1.f;
        float4 a = *(const float4*)(X + (size_t)c * 128 + ln * 4);
        s.x += p * a.x; s.y += p * a.y; s.z += p * a.z; s.w += p * a.w;
      }
      if (mode == 1) {
        float inv = 1.f / fmaxf((float)(e1 - e0), 1.f);
        s.x *= inv; s.y *= inv; s.z *= inv; s.w *= inv;
      } else if (mode == 3) {
        float inv = (e1 > e0) ? 1.f / z : 0.f;
        s.x *= inv; s.y *= inv; s.z *= inv; s.w *= inv;
      }
      storeAhl(row, ln, s);
    }
  };

  auto accum = [&](const short* __restrict__ WH, const short* __restrict__ WL) {
#pragma unroll
    for (int kg = 0; kg < 4; ++kg) {
      short8v bhi[2], blo[2];
#pragma unroll
      for (int ct = 0; ct < 2; ++ct) {
        size_t o = (size_t)(colbase + ct * 16 + cn) * 128 + kg * 32 + g * 8;
        bhi[ct] = *(const short8v*)(WH + o);
        blo[ct] = *(const short8v*)(WL + o);
      }
#pragma unroll
      for (int rt = 0; rt < 2; ++rt) {
        const int ao = (rt * 16 + cn) * 136 + kg * 32 + g * 8;
        const short8v ah = *(const short8v*)(Ah + ao);
        const short8v al = *(const short8v*)(Al + ao);
#pragma unroll
        for (int ct = 0; ct < 2; ++ct) {
          acc[rt][ct] = __builtin_amdgcn_mfma_f32_16x16x32_bf16(ah, bhi[ct], acc[rt][ct], 0, 0, 0);
          acc[rt][ct] = __builtin_amdgcn_mfma_f32_16x16x32_bf16(al, bhi[ct], acc[rt][ct], 0, 0, 0);
          acc[rt][ct] = __builtin_amdgcn_mfma_f32_16x16x32_bf16(ah, blo[ct], acc[rt][ct], 0, 0, 0);
        }
      }
    }
  };

  // ---- operand 0 ----
  if (o0.mode) {
    prefetch(o0);
    __syncthreads();
    stage_gather(o0);
  } else {
    stageA(o0.A);
  }
  __syncthreads();
  if (hasO1 && o1.mode) prefetch(o1);
  accum(o0.WH, o0.WL);
  // ---- operand 1 ----
  if (hasO1) {
    __syncthreads();
    if (o1.mode) stage_gather(o1); else stageA(o1.A);
    __syncthreads();
    accum(o1.WH, o1.WL);
  }
  __syncthreads();

  // acc -> LDS C-tile (C/D layout col=lane&15, row=(lane>>4)*4+reg)
#pragma unroll
  for (int rt = 0; rt < 2; ++rt)
#pragma unroll
    for (int ct = 0; ct < 2; ++ct)
#pragma unroll
      for (int r = 0; r < 4; ++r)
        Cf[(rt * 16 + g * 4 + r) * CF_LD + colbase + ct * 16 + cn] = acc[rt][ct][r];
  __syncthreads();

  float4* C4 = C ? (float4*)(C + (size_t)row0 * 128) : nullptr;
#pragma unroll
  for (int i = 0; i < 4; ++i) {
    int f4 = t + i * 256;
    int row = f4 >> 5, c4 = f4 & 31;
    if (row0 + row < N) {
      float4 v = *(const float4*)(Cf + row * CF_LD + c4 * 4);
      if (bias) {
        float4 bv = *(const float4*)(bias + c4 * 4);
        v.x += bv.x; v.y += bv.y; v.z += bv.z; v.w += bv.w;
      }
      if (bias2) {
        float4 bv = *(const float4*)(bias2 + c4 * 4);
        v.x += bv.x; v.y += bv.y; v.z += bv.z; v.w += bv.w;
      }
      if (addin) {
        float4 av = *(const float4*)(addin + (size_t)(row0 + row) * 128 + c4 * 4);
        v.x += av.x; v.y += av.y; v.z += av.z; v.w += av.w;
      }
      if (relu) {
        v.x = fmaxf(v.x, 0.f); v.y = fmaxf(v.y, 0.f);
        v.z = fmaxf(v.z, 0.f); v.w = fmaxf(v.w, 0.f);
      }
      if (C) C4[f4] = v;
      *(float4*)(Cf + row * CF_LD + c4 * 4) = v;   // post-activation back to LDS
      if (avec) {
        float4 av = *(const float4*)(avec + c4 * 4);
        float p = v.x * av.x + v.y * av.y + v.z * av.z + v.w * av.w;
#pragma unroll
        for (int o = 1; o < 32; o <<= 1) p += __shfl_xor(p, o);
        if (c4 == 0) adot[row0 + row] = p;
      }
      if (avec2) {
        float4 av = *(const float4*)(avec2 + c4 * 4);
        float p = v.x * av.x + v.y * av.y + v.z * av.z + v.w * av.w;
#pragma unroll
        for (int o = 1; o < 32; o <<= 1) p += __shfl_xor(p, o);
        if (c4 == 0) adot2[row0 + row] = p;
      }
    }
  }

  // ---- fused segment pool: Cf (post-act) summed per sorted-graph segment ----
  if (poolbuf) {
    if (t < TM) { int r = row0 + t; bsh[t] = (r < N) ? bvec[r] : -1; }
    __syncthreads();
    if (t < 128) {
      int c = t;
      float sum = 0.f;
      int cur = bsh[0];
      for (int r = 0; r < TM; ++r) {
        int gg = bsh[r];
        if (gg < 0) break;
        if (gg != cur) {
          atomicAdd(poolbuf + (size_t)cur * 640 + coloff + c, sum);
          sum = 0.f; cur = gg;
        }
        sum += Cf[r * CF_LD + c];
      }
      if (cur >= 0) atomicAdd(poolbuf + (size_t)cur * 640 + coloff + c, sum);
    }
  }
}

// ======================= row dots (one wave / node) =======================
__global__ void k_rowdot(const float* __restrict__ x, const float* __restrict__ a,
                         float* __restrict__ out, int N)
{
  int wid = blockIdx.x * 4 + (threadIdx.x >> 6);
  int lane = threadIdx.x & 63;
  if (wid >= N) return;
  float2 xv = ((const float2*)x)[(size_t)wid * 64 + lane];
  float2 av = ((const float2*)a)[lane];
  float v = fmaf(xv.y, av.y, xv.x * av.x);
#pragma unroll
  for (int o = 32; o > 0; o >>= 1) v += __shfl_down(v, o);
  if (lane == 0) out[wid] = v;
}

__global__ void k_rowdot2(const float* __restrict__ x, const float* __restrict__ a1,
                          const float* __restrict__ a2, float* __restrict__ o1,
                          float* __restrict__ o2, int N)
{
  int wid = blockIdx.x * 4 + (threadIdx.x >> 6);
  int lane = threadIdx.x & 63;
  if (wid >= N) return;
  float2 xv = ((const float2*)x)[(size_t)wid * 64 + lane];
  float2 av1 = ((const float2*)a1)[lane];
  float2 av2 = ((const float2*)a2)[lane];
  float v1 = fmaf(xv.y, av1.y, xv.x * av1.x);
  float v2 = fmaf(xv.y, av2.y, xv.x * av2.x);
#pragma unroll
  for (int o = 32; o > 0; o >>= 1) { v1 += __shfl_down(v1, o); v2 += __shfl_down(v2, o); }
  if (lane == 0) { o1[wid] = v1; o2[wid] = v2; }
}

// ================= batched matvec =================
struct MTab { const float* W[8]; const float* a[8]; };
__global__ __launch_bounds__(128) void k_matvec8(MTab tb, float* __restrict__ wv)
{
  __shared__ float as[128];
  int m = blockIdx.x, i = threadIdx.x;
  as[i] = tb.a[m][i];
  __syncthreads();
  const float* W = tb.W[m];
  float v = 0.f;
  for (int j = 0; j < 128; ++j) v = fmaf(W[i * 128 + j], as[j], v);
  wv[m * 128 + i] = v;
}

// ======================= batched CSR build =======================
struct HTab { const int* key[6]; int* cnt[6]; unsigned short* rank[6]; int bo[7]; int n[6]; };
__global__ void k_hist_rank_all(HTab tb) {
  int bi = blockIdx.x, ty = 0;
  while (ty < 5 && bi >= tb.bo[ty + 1]) ++ty;
  int i = (bi - tb.bo[ty]) * 256 + threadIdx.x;
  if (i < tb.n[ty])
    tb.rank[ty][i] = (unsigned short)atomicAdd(&tb.cnt[ty][tb.key[ty][i]], 1);
}

struct FTab { const int* es[6]; const int* ed[6]; const int* rp[6];
              const unsigned short* rank[6]; int* col[6]; int bo[7]; int n[6]; };
__global__ void k_fill_all(FTab tb) {
  int bi = blockIdx.x, ty = 0;
  while (ty < 5 && bi >= tb.bo[ty + 1]) ++ty;
  int e = (bi - tb.bo[ty]) * 256 + threadIdx.x;
  if (e >= tb.n[ty]) return;
  int p = tb.rp[ty][tb.ed[ty][e]] + (int)tb.rank[ty][e];
  tb.col[ty][p] = tb.es[ty][e];
}

struct STab { int* rp[6]; int* bs[6]; int n[6]; int bo[7]; };

__global__ __launch_bounds__(256) void k_scan_partial_all(STab tb) {
  __shared__ int red[256];
  int bi = blockIdx.x, ty = 0;
  while (ty < 5 && bi >= tb.bo[ty + 1]) ++ty;
  int lb = bi - tb.bo[ty];
  const int* rp = tb.rp[ty];
  const int N = tb.n[ty];
  const int t = threadIdx.x, base = lb * 4096;
  int s = 0;
  for (int i = t; i < 4096; i += 256) {
    int idx = base + i;
    if (idx < N) s += rp[idx];
  }
  red[t] = s;
  __syncthreads();
  for (int ofs = 128; ofs > 0; ofs >>= 1) {
    if (t < ofs) red[t] += red[t + ofs];
    __syncthreads();
  }
  if (t == 0) tb.bs[ty][lb] = red[0];
}

__global__ __launch_bounds__(256) void k_scan_bsums_all(STab tb) {
  __shared__ int sh[256];
  const int ty = blockIdx.x;
  const int nb = (tb.n[ty] + 4095) / 4096;
  const int t = threadIdx.x;
  int v = (t < nb) ? tb.bs[ty][t] : 0;
  sh[t] = v;
  __syncthreads();
  for (int ofs = 1; ofs < 256; ofs <<= 1) {
    int u = (t >= ofs) ? sh[t - ofs] : 0;
    __syncthreads();
    sh[t] += u;
    __syncthreads();
  }
  if (t < nb) tb.bs[ty][t] = sh[t] - v;
  if (t == 255) tb.rp[ty][tb.n[ty]] = sh[255];
}

__global__ __launch_bounds__(256) void k_scan_final_all(STab tb) {
  __shared__ int sh[4096 + 256];
  __shared__ int tsum[256];
  int bi = blockIdx.x, ty = 0;
  while (ty < 5 && bi >= tb.bo[ty + 1]) ++ty;
  int lb = bi - tb.bo[ty];
  int* rp = tb.rp[ty];
  const int N = tb.n[ty];
  const int t = threadIdx.x, base = lb * 4096;
  auto mp = [](int i) { return i + (i >> 4); };
#pragma unroll
  for (int i = 0; i < 16; ++i) {
    int idx = base + i * 256 + t;
    sh[mp(i * 256 + t)] = (idx < N) ? rp[idx] : 0;
  }
  __syncthreads();
  int s = 0;
#pragma unroll
  for (int j = 0; j < 16; ++j) s += sh[mp(t * 16 + j)];
  tsum[t] = s;
  __syncthreads();
  for (int ofs = 1; ofs < 256; ofs <<= 1) {
    int u = (t >= ofs) ? tsum[t - ofs] : 0;
    __syncthreads();
    tsum[t] += u;
    __syncthreads();
  }
  int pre = tsum[t] - s + tb.bs[ty][lb];
#pragma unroll
  for (int j = 0; j < 16; ++j) {
    int v = sh[mp(t * 16 + j)];
    sh[mp(t * 16 + j)] = pre;
    pre += v;
  }
  __syncthreads();
#pragma unroll
  for (int i = 0; i < 16; ++i) {
    int idx = base + i * 256 + t;
    if (idx < N) rp[idx] = sh[mp(i * 256 + t)];
  }
}

struct BTab { const int* b[5]; int n[5]; };
__global__ __launch_bounds__(512) void k_runptr(BTab tb, int* __restrict__ rpb_all) {
  const int ty = blockIdx.x;
  const int* b = tb.b[ty];
  const int N = tb.n[ty];
  const int t = threadIdx.x;
  int lo = 0, hi = N;
  while (lo < hi) {
    int mid = (lo + hi) >> 1;
    if (b[mid] < t) lo = mid + 1; else hi = mid;
  }
  rpb_all[ty * RPB + t] = lo;
  if (t == 0) rpb_all[ty * RPB + GNUM] = N;
}

struct DTab { const int* rp[2]; float* dis[2]; int n[2]; int bo[3]; };
__global__ void k_dis2(DTab tb) {
  int bi = blockIdx.x, ty = (bi >= tb.bo[1]) ? 1 : 0;
  int n = (bi - tb.bo[ty]) * 256 + threadIdx.x;
  if (n < tb.n[ty]) tb.dis[ty][n] = rsqrtf((float)(tb.rp[ty][n + 1] - tb.rp[ty][n]) + 1.f);
}

// ======================= final MLP (divides pooled sums by counts) ================
__global__ void k_mlp(const float* __restrict__ pool, const int* __restrict__ rpb_all,
                      const float* __restrict__ W1, const float* __restrict__ b1,
                      const float* __restrict__ W2, const float* __restrict__ b2,
                      float* __restrict__ out)
{
  __shared__ float emb[640];
  __shared__ float red[128];
  const int g = blockIdx.x, t = threadIdx.x;
  for (int i = t; i < 640; i += 128) {
    int type = i >> 7;
    int cnt = rpb_all[type * RPB + g + 1] - rpb_all[type * RPB + g];
    emb[i] = pool[(size_t)g * 640 + i] / fmaxf((float)cnt, 1.f);
  }
  __syncthreads();
  float acc = b1[t];
  for (int i = 0; i < 640; ++i) acc = fmaf(emb[i], W1[i * 128 + t], acc);
  float h = fmaxf(acc, 0.f);
  red[t] = h * W2[t];
  __syncthreads();
  for (int s = 64; s > 0; s >>= 1) {
    if (t < s) red[t] += red[t + s];
    __syncthreads();
  }
  if (t == 0) out[g] = red[0] + b2[0];
}

// ======================= host =======================
extern "C" void kernel_launch(void* const* d_in, const int* in_sizes, int n_in,
                              void* d_out, int out_size, void* d_ws, size_t ws_size,
                              hipStream_t stream)
{
  auto fin = [&](int i) { return (const float*)d_in[i]; };
  auto iin = [&](int i) { return (const int*)d_in[i]; };

  const float *x_cd = fin(0), *x_seq = fin(1), *x_anno = fin(2), *x_range = fin(3), *x_md = fin(4);
  const int *ei_seq = iin(5), *ei_anno = iin(6), *ei_range = iin(7),
            *ei_comp = iin(8), *ei_cc = iin(9), *ei_mm = iin(10);
  const int *b_cd = iin(11), *b_seq = iin(12), *b_anno = iin(13), *b_range = iin(14), *b_md = iin(15);

  const int N_CD = in_sizes[0] / HD, N_SEQ = in_sizes[1] / HD, N_ANNO = in_sizes[2] / HD,
            N_RANGE = in_sizes[3] / HD, N_MD = in_sizes[4] / HD;
  const int E_seq = in_sizes[5] / 2, E_anno = in_sizes[6] / 2, E_range = in_sizes[7] / 2,
            E_comp = in_sizes[8] / 2, E_cc = in_sizes[9] / 2, E_mm = in_sizes[10] / 2;
  const int N_OTH = max(max(N_SEQ, N_ANNO), N_RANGE);

  auto WLm = [&](int i, int l) { return fin(i) + (size_t)l * HD * HD; };
  auto WLv = [&](int i, int l) { return fin(i) + (size_t)l * HD; };

  // ---- workspace layout ----
  float* ws = (float*)d_ws;
  size_t off = 0;
  auto alloc = [&](size_t n) { float* p = ws + off; off += (n + 3) & ~(size_t)3; return p; };
  float* xcd1 = alloc((size_t)N_CD * HD);
  float* xmd1 = alloc((size_t)N_MD * HD);
  float* xoth = alloc((size_t)N_OTH * HD);
  float* t1   = alloc((size_t)N_CD * HD);
  float* sA = alloc((size_t)N_CD);
  float* sB = alloc((size_t)N_CD);
  float* sC = alloc((size_t)N_CD);
  float* sD = alloc((size_t)N_CD);
  float* sE = alloc((size_t)N_CD);
  float* sF = alloc((size_t)N_CD);
  float* dis_cc = alloc((size_t)N_CD);
  float* dis_mm = alloc((size_t)N_MD);
  float* wv8 = alloc(8 * HD);
  float* pool = alloc((size_t)GNUM * 5 * HD);
  short* whi = (short*)(ws + off); off += (size_t)16 * 16384 / 2;
  short* wlo = (short*)(ws + off); off += (size_t)16 * 16384 / 2;
  auto alloci = [&](size_t n) { int* p = (int*)(ws + off); off += (n + 3) & ~(size_t)3; return p; };
  int* bsall = alloci(6 * 256);
  int* rpb_all = alloci(5 * RPB);
  int Nds[6] = {N_SEQ, N_ANNO, N_RANGE, N_CD, N_CD, N_MD};
  int Es[6]  = {E_seq, E_anno, E_range, E_comp, E_cc, E_mm};
  int* rps[6];
  int* rp0 = alloci(0);
  { size_t tot = 0; for (int i = 0; i < 6; ++i) tot += (size_t)Nds[i] + 1;
    int* p = alloci(tot); rp0 = p;
    for (int i = 0; i < 6; ++i) { rps[i] = p; p += Nds[i] + 1; } }
  size_t rp_tot_bytes = 0; for (int i = 0; i < 6; ++i) rp_tot_bytes += ((size_t)Nds[i] + 1) * 4;
  unsigned short* ranks[6];
  for (int i = 0; i < 6; ++i) ranks[i] = (unsigned short*)alloci(((size_t)Es[i] + 1) / 2);
  int* cols[6];  for (int i = 0; i < 6; ++i) cols[i] = alloci((size_t)Es[i]);
  (void)n_in;

  if (off * sizeof(float) > ws_size) {
    hipMemsetAsync(d_out, 0, (size_t)out_size * sizeof(float), stream);
    return;
  }

  auto ew = [&](size_t elems) { return dim3((unsigned)((elems + 255) / 256)); };
  auto nw = [&](int N) { return dim3((unsigned)((N + 3) / 4)); };

  // ---- pool accumulator must start at zero ----
  hipMemsetAsync(pool, 0, (size_t)GNUM * 5 * HD * sizeof(float), stream);

  // ---- pre-split all GEMM weights (slots: 0:16 1:18 2:19 3:21 4:22 5:27 6:32 7:34)
  WTab tab;
  tab.p[0] = fin(16); tab.p[1] = fin(18); tab.p[2] = fin(19); tab.p[3] = fin(21);
  tab.p[4] = fin(22); tab.p[5] = fin(27); tab.p[6] = fin(32); tab.p[7] = fin(34);
  k_split_w<<<dim3(1024), dim3(256), 0, stream>>>(tab, whi, wlo);

  // ---- 8 GAT matvecs: s/d for comp L0,L1 and range L0,L1 ----
  MTab mt;
  mt.W[0] = WLm(22, 0); mt.a[0] = WLv(24, 0);
  mt.W[1] = WLm(23, 0); mt.a[1] = WLv(25, 0);
  mt.W[2] = WLm(22, 1); mt.a[2] = WLv(24, 1);
  mt.W[3] = WLm(23, 1); mt.a[3] = WLv(25, 1);
  mt.W[4] = WLm(27, 0); mt.a[4] = WLv(29, 0);
  mt.W[5] = WLm(28, 0); mt.a[5] = WLv(30, 0);
  mt.W[6] = WLm(27, 1); mt.a[6] = WLv(29, 1);
  mt.W[7] = WLm(28, 1); mt.a[7] = WLv(30, 1);
  k_matvec8<<<dim3(8), dim3(128), 0, stream>>>(mt, wv8);

  // ---- input-side attention scalars ----
  k_rowdot<<<nw(N_MD), dim3(256), 0, stream>>>(x_md, wv8 + 0 * 128, sA, N_MD);
  k_rowdot2<<<nw(N_CD), dim3(256), 0, stream>>>(x_cd, wv8 + 1 * 128, wv8 + 4 * 128,
                                                sB, sC, N_CD);
  k_rowdot<<<nw(N_RANGE), dim3(256), 0, stream>>>(x_range, wv8 + 5 * 128, sD, N_RANGE);

  // ---- run-pointers for sorted batch vectors ----
  {
    BTab bt;
    bt.b[0] = b_cd; bt.n[0] = N_CD;  bt.b[1] = b_seq; bt.n[1] = N_SEQ;
    bt.b[2] = b_anno; bt.n[2] = N_ANNO;  bt.b[3] = b_range; bt.n[3] = N_RANGE;
    bt.b[4] = b_md; bt.n[4] = N_MD;
    k_runptr<<<dim3(5), dim3(512), 0, stream>>>(bt, rpb_all);
  }

  // ---- batched CSR build ----
  const int* ess[6] = {ei_seq, ei_anno, ei_range, ei_comp, ei_cc, ei_mm};
  const int* eds[6] = {ei_seq + E_seq, ei_anno + E_anno, ei_range + E_range,
                       ei_comp + E_comp, ei_cc + E_cc, ei_mm + E_mm};
  hipMemsetAsync(rp0, 0, rp_tot_bytes, stream);
  {
    HTab ht; int b = 0;
    for (int i = 0; i < 6; ++i) {
      ht.key[i] = eds[i]; ht.cnt[i] = rps[i]; ht.rank[i] = ranks[i];
      ht.bo[i] = b; b += (Es[i] + 255) / 256; ht.n[i] = Es[i];
    }
    ht.bo[6] = b;
    k_hist_rank_all<<<dim3(b), dim3(256), 0, stream>>>(ht);
  }
  {
    STab st; int b = 0;
    for (int i = 0; i < 6; ++i) {
      st.rp[i] = rps[i]; st.bs[i] = bsall + i * 256;
      st.n[i] = Nds[i]; st.bo[i] = b; b += (Nds[i] + 4095) / 4096;
    }
    st.bo[6] = b;
    k_scan_partial_all<<<dim3(b), dim3(256), 0, stream>>>(st);
    k_scan_bsums_all<<<dim3(6), dim3(256), 0, stream>>>(st);
    k_scan_final_all<<<dim3(b), dim3(256), 0, stream>>>(st);
  }
  {
    FTab ft; int b = 0;
    for (int i = 0; i < 6; ++i) {
      ft.es[i] = ess[i]; ft.ed[i] = eds[i]; ft.rp[i] = rps[i]; ft.rank[i] = ranks[i];
      ft.col[i] = cols[i]; ft.bo[i] = b; b += (Es[i] + 255) / 256; ft.n[i] = Es[i];
    }
    ft.bo[6] = b;
    k_fill_all<<<dim3(b), dim3(256), 0, stream>>>(ft);
  }
  int *rp_seq = rps[0], *rp_anno = rps[1], *rp_range = rps[2],
      *rp_comp = rps[3], *rp_cc = rps[4], *rp_mm = rps[5];
  int *col_seq = cols[0], *col_anno = cols[1], *col_range = cols[2],
      *col_comp = cols[3], *col_cc = cols[4], *col_mm = cols[5];
  {
    DTab dt;
    dt.rp[0] = rp_cc; dt.dis[0] = dis_cc; dt.n[0] = N_CD;
    dt.rp[1] = rp_mm; dt.dis[1] = dis_mm; dt.n[1] = N_MD;
    dt.bo[0] = 0; dt.bo[1] = (N_CD + 255) / 256;
    dt.bo[2] = dt.bo[1] + (N_MD + 255) / 256;
    k_dis2<<<dim3(dt.bo[2]), dim3(256), 0, stream>>>(dt);
  }

  auto WHp = [&](int sidx, int layer) { return whi + (size_t)(sidx * 2 + layer) * 16384; };
  auto WLp = [&](int sidx, int layer) { return wlo + (size_t)(sidx * 2 + layer) * 16384; };

  auto mkop = [&](int mode, const float* A, int sidx, int layer,
                  const int* grp, const int* gcol,
                  const float* wsrc, const float* rowsc) {
    COp o;
    o.A = A; o.WH = WHp(sidx, layer); o.WL = WLp(sidx, layer);
    o.grp = grp; o.gcol = gcol; o.wsrc = wsrc; o.rowsc = rowsc; o.mode = mode;
    return o;
  };
  auto launch = [&](COp o0, COp o1, int hasO1, float* C, const float* bias,
                    const float* bias2, const float* addin, int N, int relu,
                    const float* avec, float* adot, const float* avec2, float* adot2,
                    const int* bvec, int coloff) {
    k_gemm_conv<<<dim3((N + TM - 1) / TM), dim3(256), 0, stream>>>(
        o0, o1, hasO1, C, bias, bias2, addin, N, relu, avec, adot, avec2, adot2,
        bvec, bvec ? pool : nullptr, coloff);
  };
  COp nop = {};

  // ---------- L0 fused CD: GAT(x_md,comp) + GCN(x_cd,cc) -> xcd1 ----------
  launch(mkop(3, x_md, 4, 0, rp_comp, col_comp, sA, sB),
         mkop(2, x_cd, 6, 0, rp_cc, col_cc, dis_cc, dis_cc), 1,
         xcd1, WLv(26, 0), WLv(33, 0), nullptr, N_CD, 1,
         wv8 + 3 * 128, sB, wv8 + 6 * 128, sE, nullptr, 0);
  // ---------- L0 mm GCN -> xmd1 (dot: comp1 sAs -> sA) ----------
  launch(mkop(2, x_md, 7, 0, rp_mm, col_mm, dis_mm, dis_mm), nop, 0,
         xmd1, WLv(35, 0), nullptr, nullptr, N_MD, 1,
         wv8 + 2 * 128, sA, nullptr, nullptr, nullptr, 0);
  // ---------- L1 fused CD: GAT(xmd1,comp) + GCN(xcd1,cc) -> POOL(type 0) ----------
  launch(mkop(3, xmd1, 4, 1, rp_comp, col_comp, sA, sB),
         mkop(2, xcd1, 6, 1, rp_cc, col_cc, dis_cc, dis_cc), 1,
         nullptr, WLv(26, 1), WLv(33, 1), nullptr, N_CD, 1,
         nullptr, nullptr, nullptr, nullptr, b_cd, 0 * HD);
  // ---------- L1 mm GCN -> POOL(type 4) ----------
  launch(mkop(2, xmd1, 7, 1, rp_mm, col_mm, dis_mm, dis_mm), nop, 0,
         nullptr, WLv(35, 1), nullptr, nullptr, N_MD, 1,
         nullptr, nullptr, nullptr, nullptr, b_md, 4 * HD);

  // ---------- SEQ (SAGE) ----------
  launch(mkop(1, x_cd, 0, 0, rp_seq, col_seq, nullptr, nullptr),
         mkop(0, x_seq, 1, 0, nullptr, nullptr, nullptr, nullptr), 1,
         xoth, WLv(17, 0), nullptr, nullptr, N_SEQ, 1,
         nullptr, nullptr, nullptr, nullptr, nullptr, 0);
  launch(mkop(1, xcd1, 0, 1, rp_seq, col_seq, nullptr, nullptr),
         mkop(0, xoth, 1, 1, nullptr, nullptr, nullptr, nullptr), 1,
         nullptr, WLv(17, 1), nullptr, nullptr, N_SEQ, 1,
         nullptr, nullptr, nullptr, nullptr, b_seq, 1 * HD);
  // ---------- ANNO ----------
  launch(mkop(1, x_cd, 2, 0, rp_anno, col_anno, nullptr, nullptr),
         mkop(0, x_anno, 3, 0, nullptr, nullptr, nullptr, nullptr), 1,
         t1, WLv(20, 0), nullptr, nullptr, N_ANNO, 1,
         nullptr, nullptr, nullptr, nullptr, nullptr, 0);
  launch(mkop(1, xcd1, 2, 1, rp_anno, col_anno, nullptr, nullptr),
         mkop(0, t1, 3, 1, nullptr, nullptr, nullptr, nullptr), 1,
         nullptr, WLv(20, 1), nullptr, nullptr, N_ANNO, 1,
         nullptr, nullptr, nullptr, nullptr, b_anno, 2 * HD);
  // ---------- RANGE (GAT) ----------
  launch(mkop(3, x_cd, 5, 0, rp_range, col_range, sC, sD), nop, 0,
         xoth, WLv(31, 0), nullptr, nullptr, N_RANGE, 1,
         wv8 + 7 * 128, sF, nullptr, nullptr, nullptr, 0);
  launch(mkop(3, xcd1, 5, 1, rp_range, col_range, sE, sF), nop, 0,
         nullptr, WLv(31, 1), nullptr, nullptr, N_RANGE, 1,
         nullptr, nullptr, nullptr, nullptr, b_range, 3 * HD);

  k_mlp<<<dim3(GNUM), dim3(128), 0, stream>>>(
      pool, rpb_all, fin(36), fin(37), fin(38), fin(39), (float*)d_out);
}